// Round 1
// 2460.457 us; speedup vs baseline: 1.5670x; 1.5670x over previous
//
#include <hip/hip_runtime.h>
#include <math.h>

// Problem constants
#define TSTEPS 19   // T-1 decode steps
#define NB 64       // batch
#define NS 64       // src len
#define NT 20       // tgt len
#define NH 512      // hidden
#define NE 256      // emb dim
#define NV 32000    // vocab

// ---------------------------------------------------------------------------
// System-scope (L2-bypassing) memory helpers. All cross-block intra-kernel
// dataflow uses these, so NO buffer_wbl2/buffer_inv cache maintenance is ever
// required (the former grid.sync flushed L2 38x per dispatch -> 21MB/step
// refetch, the dominant cost). Read-only weights stay in warm L2.
// ---------------------------------------------------------------------------
__device__ __forceinline__ float ldg_sys(const float* p) {
  return __hip_atomic_load(p, __ATOMIC_RELAXED, __HIP_MEMORY_SCOPE_SYSTEM);
}
__device__ __forceinline__ void stg_sys(float* p, float v) {
  __hip_atomic_store(p, v, __ATOMIC_RELAXED, __HIP_MEMORY_SCOPE_SYSTEM);
}
__device__ __forceinline__ int flag_ld(const int* f) {
  return __hip_atomic_load(f, __ATOMIC_RELAXED, __HIP_MEMORY_SCOPE_SYSTEM);
}
__device__ __forceinline__ void vmfence() {
  asm volatile("s_waitcnt vmcnt(0)" ::: "memory");
}
// block-wide: all prior (bypassing) stores drained, then one arrival tick
__device__ __forceinline__ void publish(int* f) {
  vmfence();
  __syncthreads();
  if (threadIdx.x == 0)
    __hip_atomic_fetch_add(f, 1, __ATOMIC_RELAXED, __HIP_MEMORY_SCOPE_SYSTEM);
  asm volatile("" ::: "memory");
}
// block-wide: wait until counter reaches target
__device__ __forceinline__ void waitf(const int* f, int target) {
  if (threadIdx.x == 0) {
    while (flag_ld(f) < target) __builtin_amdgcn_s_sleep(2);
  }
  __syncthreads();
  asm volatile("" ::: "memory");
}

// ---------------------------------------------------------------------------
// Generic fp32 linear: C[M,N] = A[M,K] @ W[N,K]^T (+bias). BM=64, BN=128,
// BK=16; 256 threads; 4x8 per thread. (enc_proj and enc_proj2)
// ---------------------------------------------------------------------------
__global__ __launch_bounds__(256) void linear_kernel(
    const float* __restrict__ A, int lda,
    const float* __restrict__ W, int ldw,
    const float* __restrict__ bias,
    float* __restrict__ C, int ldc,
    int K, int act)
{
  __shared__ float As[16][68];
  __shared__ float Ws[16][132];
  const int tid = threadIdx.x;
  const int m0 = blockIdx.y * 64;
  const int n0 = blockIdx.x * 128;
  const int lr = tid >> 2;
  const int lc = (tid & 3) << 2;
  const int tm = tid & 15;
  const int tn = tid >> 4;

  float acc[4][8];
#pragma unroll
  for (int i = 0; i < 4; ++i)
#pragma unroll
    for (int j = 0; j < 8; ++j) acc[i][j] = 0.f;

  const float* Ar  = A + (size_t)(m0 + lr) * lda + lc;
  const float* Wr0 = W + (size_t)(n0 + lr) * ldw + lc;
  const float* Wr1 = W + (size_t)(n0 + 64 + lr) * ldw + lc;

  for (int kk = 0; kk < K; kk += 16) {
    float4 av = *(const float4*)(Ar + kk);
    float4 w0 = *(const float4*)(Wr0 + kk);
    float4 w1 = *(const float4*)(Wr1 + kk);
    As[lc+0][lr] = av.x; As[lc+1][lr] = av.y; As[lc+2][lr] = av.z; As[lc+3][lr] = av.w;
    Ws[lc+0][lr] = w0.x; Ws[lc+1][lr] = w0.y; Ws[lc+2][lr] = w0.z; Ws[lc+3][lr] = w0.w;
    Ws[lc+0][64+lr] = w1.x; Ws[lc+1][64+lr] = w1.y; Ws[lc+2][64+lr] = w1.z; Ws[lc+3][64+lr] = w1.w;
    __syncthreads();
#pragma unroll
    for (int k = 0; k < 16; ++k) {
      float4 a4 = *(const float4*)&As[k][tm * 4];
      float4 b4 = *(const float4*)&Ws[k][tn * 8];
      float4 b5 = *(const float4*)&Ws[k][tn * 8 + 4];
      float a[4] = {a4.x, a4.y, a4.z, a4.w};
      float b[8] = {b4.x, b4.y, b4.z, b4.w, b5.x, b5.y, b5.z, b5.w};
#pragma unroll
      for (int i = 0; i < 4; ++i)
#pragma unroll
        for (int j = 0; j < 8; ++j)
          acc[i][j] = fmaf(a[i], b[j], acc[i][j]);
    }
    __syncthreads();
  }

#pragma unroll
  for (int i = 0; i < 4; ++i) {
    int m = m0 + tm * 4 + i;
    float* crow = C + (size_t)m * ldc + n0 + tn * 8;
    float vv[8];
#pragma unroll
    for (int j = 0; j < 8; ++j) {
      float v = acc[i][j];
      if (bias) v += bias[n0 + tn * 8 + j];
      if (act == 1) v = tanhf(v);
      vv[j] = v;
    }
    *(float4*)(crow)     = make_float4(vv[0], vv[1], vv[2], vv[3]);
    *(float4*)(crow + 4) = make_float4(vv[4], vv[5], vv[6], vv[7]);
  }
}

// ---------------------------------------------------------------------------
// gi_emb[t*64+b][:] = emb[tgt[b][t]] @ W_ih[:, :256]^T + b_ih   (1216 x 1536)
// ---------------------------------------------------------------------------
__global__ __launch_bounds__(256) void emb_linear_kernel(
    const float* __restrict__ emb, const int* __restrict__ tgt,
    const float* __restrict__ W_ih, const float* __restrict__ b_ih,
    float* __restrict__ C)
{
  __shared__ float As[16][68];
  __shared__ float Ws[16][132];
  const int tid = threadIdx.x;
  const int m0 = blockIdx.y * 64;
  const int n0 = blockIdx.x * 128;
  const int lr = tid >> 2;
  const int lc = (tid & 3) << 2;
  const int tm = tid & 15;
  const int tn = tid >> 4;

  float acc[4][8];
#pragma unroll
  for (int i = 0; i < 4; ++i)
#pragma unroll
    for (int j = 0; j < 8; ++j) acc[i][j] = 0.f;

  const int row = m0 + lr;                 // row = t*64 + b
  const int tok = tgt[(row & 63) * NT + (row >> 6)];
  const float* Ar  = emb + (size_t)tok * NE + lc;
  const float* Wr0 = W_ih + (size_t)(n0 + lr) * 768 + lc;
  const float* Wr1 = W_ih + (size_t)(n0 + 64 + lr) * 768 + lc;

  for (int kk = 0; kk < NE; kk += 16) {
    float4 av = *(const float4*)(Ar + kk);
    float4 w0 = *(const float4*)(Wr0 + kk);
    float4 w1 = *(const float4*)(Wr1 + kk);
    As[lc+0][lr] = av.x; As[lc+1][lr] = av.y; As[lc+2][lr] = av.z; As[lc+3][lr] = av.w;
    Ws[lc+0][lr] = w0.x; Ws[lc+1][lr] = w0.y; Ws[lc+2][lr] = w0.z; Ws[lc+3][lr] = w0.w;
    Ws[lc+0][64+lr] = w1.x; Ws[lc+1][64+lr] = w1.y; Ws[lc+2][64+lr] = w1.z; Ws[lc+3][64+lr] = w1.w;
    __syncthreads();
#pragma unroll
    for (int k = 0; k < 16; ++k) {
      float4 a4 = *(const float4*)&As[k][tm * 4];
      float4 b4 = *(const float4*)&Ws[k][tn * 8];
      float4 b5 = *(const float4*)&Ws[k][tn * 8 + 4];
      float a[4] = {a4.x, a4.y, a4.z, a4.w};
      float b[8] = {b4.x, b4.y, b4.z, b4.w, b5.x, b5.y, b5.z, b5.w};
#pragma unroll
      for (int i = 0; i < 4; ++i)
#pragma unroll
        for (int j = 0; j < 8; ++j)
          acc[i][j] = fmaf(a[i], b[j], acc[i][j]);
    }
    __syncthreads();
  }

#pragma unroll
  for (int i = 0; i < 4; ++i) {
    int m = m0 + tm * 4 + i;
    float* crow = C + (size_t)m * 1536 + n0 + tn * 8;
    float vv[8];
#pragma unroll
    for (int j = 0; j < 8; ++j) vv[j] = acc[i][j] + b_ih[n0 + tn * 8 + j];
    *(float4*)(crow)     = make_float4(vv[0], vv[1], vv[2], vv[3]);
    *(float4*)(crow + 4) = make_float4(vv[4], vv[5], vv[6], vv[7]);
  }
}

// ---------------------------------------------------------------------------
// Logits GEMM with XCD-ownership swizzle. C[1216,32000] = A @ W_out^T + b_out.
// ---------------------------------------------------------------------------
__global__ __launch_bounds__(256) void logits_kernel(
    const float* __restrict__ A, const float* __restrict__ W,
    const float* __restrict__ bias, float* __restrict__ C)
{
  const int bfl = blockIdx.x;
  const int xcd = bfl & 7;
  const int jj = bfl >> 3;
  const int mt = jj % 19;
  const int nt = xcd * 32 + jj / 19;
  if (nt >= 250) return;          // uniform whole-block exit before barriers
  const int m0 = mt * 64;
  const int n0 = nt * 128;

  __shared__ float As[16][68];
  __shared__ float Ws[16][132];
  const int tid = threadIdx.x;
  const int lr = tid >> 2;
  const int lc = (tid & 3) << 2;
  const int tm = tid & 15;
  const int tn = tid >> 4;

  float acc[4][8];
#pragma unroll
  for (int i = 0; i < 4; ++i)
#pragma unroll
    for (int j = 0; j < 8; ++j) acc[i][j] = 0.f;

  const float* Ar  = A + (size_t)(m0 + lr) * NH + lc;
  const float* Wr0 = W + (size_t)(n0 + lr) * NH + lc;
  const float* Wr1 = W + (size_t)(n0 + 64 + lr) * NH + lc;

  for (int kk = 0; kk < NH; kk += 16) {
    float4 av = *(const float4*)(Ar + kk);
    float4 w0 = *(const float4*)(Wr0 + kk);
    float4 w1 = *(const float4*)(Wr1 + kk);
    As[lc+0][lr] = av.x; As[lc+1][lr] = av.y; As[lc+2][lr] = av.z; As[lc+3][lr] = av.w;
    Ws[lc+0][lr] = w0.x; Ws[lc+1][lr] = w0.y; Ws[lc+2][lr] = w0.z; Ws[lc+3][lr] = w0.w;
    Ws[lc+0][64+lr] = w1.x; Ws[lc+1][64+lr] = w1.y; Ws[lc+2][64+lr] = w1.z; Ws[lc+3][64+lr] = w1.w;
    __syncthreads();
#pragma unroll
    for (int k = 0; k < 16; ++k) {
      float4 a4 = *(const float4*)&As[k][tm * 4];
      float4 b4 = *(const float4*)&Ws[k][tn * 8];
      float4 b5 = *(const float4*)&Ws[k][tn * 8 + 4];
      float a[4] = {a4.x, a4.y, a4.z, a4.w};
      float b[8] = {b4.x, b4.y, b4.z, b4.w, b5.x, b5.y, b5.z, b5.w};
#pragma unroll
      for (int i = 0; i < 4; ++i)
#pragma unroll
        for (int j = 0; j < 8; ++j)
          acc[i][j] = fmaf(a[i], b[j], acc[i][j]);
    }
    __syncthreads();
  }

#pragma unroll
  for (int i = 0; i < 4; ++i) {
    int m = m0 + tm * 4 + i;
    float* crow = C + (size_t)m * NV + n0 + tn * 8;
    float vv[8];
#pragma unroll
    for (int j = 0; j < 8; ++j) vv[j] = acc[i][j] + bias[n0 + tn * 8 + j];
    *(float4*)(crow)     = make_float4(vv[0], vv[1], vv[2], vv[3]);
    *(float4*)(crow + 4) = make_float4(vv[4], vv[5], vv[6], vv[7]);
  }
}

// ---------------------------------------------------------------------------
// Shared 64m x 16n GEMM tile with K-chunked LDS staging, used inside the
// recurrence. A is [64][512]. AMODE 0: cached float4 loads (read-only input);
// AMODE 1: system-scope scalar loads (cross-block data);
// AMODE 2: A element = tanh(sys(Aa)+sys(Ab)+sys(Ac))  (attn recomputed).
// Output: 4 floats/thread via system-scope stores (cross-block consumers).
// ---------------------------------------------------------------------------
template <int AMODE>
__device__ __forceinline__ void gemm_tile(
    const float* __restrict__ Aa, const float* __restrict__ Ab,
    const float* __restrict__ Ac,
    const float* __restrict__ W, int ldw, const float* __restrict__ bias,
    float* __restrict__ Cout, int ldc, int n0, int k0, int KC,
    float (*As)[68], float (*Ws)[68])
{
  const int tid = threadIdx.x;
  const int am = tid >> 2, ac = (tid & 3) << 4;
  const int wn = tid >> 4, wc = (tid & 15) << 2;
  const int m = tid & 63, nq = tid >> 6;
  float acc[4] = {0.f, 0.f, 0.f, 0.f};
  for (int kk = 0; kk < KC; kk += 64) {
    const int kb = k0 + kk;
    if (AMODE == 0) {
#pragma unroll
      for (int u = 0; u < 4; ++u)
        *(float4*)&As[am][ac + 4 * u] =
            *(const float4*)(Aa + (size_t)am * NH + kb + ac + 4 * u);
    } else if (AMODE == 1) {
#pragma unroll
      for (int u = 0; u < 16; ++u)
        As[am][ac + u] = ldg_sys(Aa + (size_t)am * NH + kb + ac + u);
    } else {
#pragma unroll
      for (int u = 0; u < 16; ++u) {
        size_t idx = (size_t)am * NH + kb + ac + u;
        As[am][ac + u] =
            tanhf(ldg_sys(Aa + idx) + ldg_sys(Ab + idx) + ldg_sys(Ac + idx));
      }
    }
    *(float4*)&Ws[wn][wc] = *(const float4*)(W + (size_t)(n0 + wn) * ldw + kb + wc);
    __syncthreads();
#pragma unroll
    for (int q = 0; q < 16; ++q) {
      float4 a4 = *(const float4*)&As[m][q * 4];
#pragma unroll
      for (int j = 0; j < 4; ++j) {
        float4 w4 = *(const float4*)&Ws[nq * 4 + j][q * 4];
        acc[j] = fmaf(a4.x, w4.x, acc[j]);
        acc[j] = fmaf(a4.y, w4.y, acc[j]);
        acc[j] = fmaf(a4.z, w4.z, acc[j]);
        acc[j] = fmaf(a4.w, w4.w, acc[j]);
      }
    }
    __syncthreads();
  }
#pragma unroll
  for (int j = 0; j < 4; ++j) {
    float v = acc[j];
    if (bias) v += bias[n0 + nq * 4 + j];
    stg_sys(Cout + (size_t)m * ldc + n0 + nq * 4 + j, v);
  }
}

// ---------------------------------------------------------------------------
// Recurrence, flag-chained (NO grid.sync, NO L2 flushes).
// 256 blocks x 256 threads, cooperative (co-residency guarantee only).
// Per iteration t:
//  rows (blk<64, b=blk):  wait gi/gh -> gates -> h^{t+1} (LDS + sys) ->
//      flag hflag[t+1] -> scores -> softmax -> ctx-part (enc_proj2 trick,
//      replaces the 2MB/CU W_concat stream) -> u-tile (Wc_h @ h, split-K2)
//      -> flag uflag[t]
//  blk 64..255: wait hflag[t+1] -> gh^{t+1} = h @ W_hh^T (96 tiles x splitK2)
//      -> flag ghflag[t+1]
//  blk 0..191:  wait uflag[t] -> gi^{t+1} = tanh(u0+u1+cp) @ W_ihh^T
//      (96 tiles x splitK2) -> flag giflag[t+1]
//  blk 192..255: wait uflag[t] -> attn_arr[t] = tanh(u0+u1+cp)  (for logits)
// u/ctxp double-buffered by t&1; giA2/ghA2/hglob single-buffered (safe: all
// overwrites are gated through the flag chain; see analysis in session log).
// ---------------------------------------------------------------------------
__global__ __launch_bounds__(256) void recur_kernel(
    const float* __restrict__ gi_emb, float* __restrict__ giA2,
    float* __restrict__ ghA2, float* __restrict__ hglob,
    float* __restrict__ ubuf, float* __restrict__ ctxp,
    float* __restrict__ attn_arr, const float* __restrict__ enc_proj,
    const float* __restrict__ enc_proj2, const float* __restrict__ enc_final,
    const int* __restrict__ len_src, const float* __restrict__ W_ih,
    const float* __restrict__ W_hh, const float* __restrict__ b_hh,
    const float* __restrict__ W_concat, const float* __restrict__ b_concat,
    int* __restrict__ flags)
{
  const int blk = blockIdx.x;
  const int tid = threadIdx.x;
  __shared__ float As[64][68];
  __shared__ float Ws[16][68];
  __shared__ float hstate[NH];
  __shared__ float scs[NS];
  __shared__ float aw[NS];

  int* hflag  = flags;             // slot (t+1)*32, target 64
  int* ghflag = flags + 1024;      // slot t*32, target 192
  int* giflag = flags + 2048;      // slot t*32, target 192
  int* uflag  = flags + 3072;      // slot t*32, target 64

  if (blk < 64) {
    hstate[tid]       = enc_final[(size_t)blk * NH + tid];
    hstate[tid + 256] = enc_final[(size_t)blk * NH + tid + 256];
    __syncthreads();
  } else {
    // prologue: gh^0 = enc_final @ W_hh^T  (cached A, split-K2)
    const int j2 = blk - 64;
    const int n0 = (j2 >> 1) * 16, kh = j2 & 1;
    gemm_tile<0>(enc_final, nullptr, nullptr, W_hh, NH, nullptr,
                 ghA2 + kh * 98304, 1536, n0, kh * 256, 256, As, Ws);
    publish(ghflag + 0);
  }

  for (int t = 0; t < TSTEPS; ++t) {
    const int par = t & 1;
    float* u0 = ubuf + par * 65536;
    float* u1 = u0 + 32768;
    float* cp = ctxp + par * 32768;

    if (blk < 64) {
      const int b = blk;
      if (t > 0) waitf(giflag + t * 32, 192);
      waitf(ghflag + t * 32, 192);
      // ---- GRU gates: h^{t+1} ----
      const float* ge = gi_emb + (size_t)(t * NB + b) * 1536;
#pragma unroll
      for (int hh = 0; hh < 2; ++hh) {
        const int j = tid + hh * 256;
        const size_t base = (size_t)b * 1536 + j;
        float gr = ge[j]        + ldg_sys(giA2 + base)          + ldg_sys(giA2 + 98304 + base);
        float gz = ge[512 + j]  + ldg_sys(giA2 + base + 512)    + ldg_sys(giA2 + 98304 + base + 512);
        float gn = ge[1024 + j] + ldg_sys(giA2 + base + 1024)   + ldg_sys(giA2 + 98304 + base + 1024);
        float hr = b_hh[j]        + ldg_sys(ghA2 + base)        + ldg_sys(ghA2 + 98304 + base);
        float hz = b_hh[512 + j]  + ldg_sys(ghA2 + base + 512)  + ldg_sys(ghA2 + 98304 + base + 512);
        float hn = b_hh[1024 + j] + ldg_sys(ghA2 + base + 1024) + ldg_sys(ghA2 + 98304 + base + 1024);
        float r = 1.f / (1.f + expf(-(gr + hr)));
        float z = 1.f / (1.f + expf(-(gz + hz)));
        float n = tanhf(gn + r * hn);
        float h = (1.f - z) * n + z * hstate[j];
        hstate[j] = h;
        stg_sys(hglob + (size_t)b * NH + j, h);
      }
      publish(hflag + (t + 1) * 32);
      // ---- attention scores (own row only; cached enc_proj, warm L2) ----
      {
        const int s = tid >> 2, sub = tid & 3;
        const float* ep = enc_proj + ((size_t)s * NB + b) * NH + sub * 4;
        float acc = 0.f;
#pragma unroll 8
        for (int i = 0; i < 32; ++i) {
          float4 e4 = *(const float4*)(ep + i * 16);
          float4 h4 = *(const float4*)&hstate[i * 16 + sub * 4];
          acc = fmaf(e4.x, h4.x, acc); acc = fmaf(e4.y, h4.y, acc);
          acc = fmaf(e4.z, h4.z, acc); acc = fmaf(e4.w, h4.w, acc);
        }
        acc += __shfl_xor(acc, 1);
        acc += __shfl_xor(acc, 2);
        if (sub == 0) scs[s] = acc;
      }
      __syncthreads();
      // ---- masked softmax (wave 0) ----
      if (tid < 64) {
        const int len = len_src[b];
        float v = (tid < len) ? scs[tid] : -1e9f;
        float mm = v;
        for (int off = 32; off >= 1; off >>= 1) mm = fmaxf(mm, __shfl_xor(mm, off));
        float e = expf(v - mm);
        float ssum = e;
        for (int off = 32; off >= 1; off >>= 1) ssum += __shfl_xor(ssum, off);
        aw[tid] = e / ssum;
      }
      __syncthreads();
      // ---- ctx-part: sum_s aw[s] * enc_proj2[s][b][:]  (== Wc_c @ ctx) ----
      {
        float c0 = 0.f, c1 = 0.f;
#pragma unroll 4
        for (int s2 = 0; s2 < NS; ++s2) {
          const float w = aw[s2];
          const float* e2 = enc_proj2 + ((size_t)s2 * NB + b) * NH;
          c0 = fmaf(w, e2[tid], c0);
          c1 = fmaf(w, e2[tid + 256], c1);
        }
        stg_sys(cp + (size_t)b * NH + tid, c0);
        stg_sys(cp + (size_t)b * NH + tid + 256, c1);
      }
      // ---- u-tile: u = h^{t+1} @ Wc_h^T (+b_concat on kh==0), split-K2 ----
      waitf(hflag + (t + 1) * 32, 64);
      {
        const int n0 = (blk >> 1) * 16, kh = blk & 1;
        gemm_tile<1>(hglob, nullptr, nullptr, W_concat, 2 * NH,
                     kh == 0 ? b_concat : nullptr,
                     kh == 0 ? u0 : u1, NH, n0, kh * 256, 256, As, Ws);
      }
      publish(uflag + t * 32);
    } else if (t + 1 < TSTEPS) {
      // ---- gh^{t+1} = h^{t+1} @ W_hh^T  (96 tiles x split-K2) ----
      waitf(hflag + (t + 1) * 32, 64);
      const int j2 = blk - 64;
      const int n0 = (j2 >> 1) * 16, kh = j2 & 1;
      gemm_tile<1>(hglob, nullptr, nullptr, W_hh, NH, nullptr,
                   ghA2 + kh * 98304, 1536, n0, kh * 256, 256, As, Ws);
      publish(ghflag + (t + 1) * 32);
    }

    if (blk < 192) {
      if (t + 1 < TSTEPS) {
        // ---- gi^{t+1} = tanh(u0+u1+cp) @ W_ih[:,256:]^T  (split-K2) ----
        waitf(uflag + t * 32, 64);
        const int n0 = (blk >> 1) * 16, kh = blk & 1;
        gemm_tile<2>(u0, u1, cp, W_ih + NE, NE + NH, nullptr,
                     giA2 + kh * 98304, 1536, n0, kh * 256, 256, As, Ws);
        publish(giflag + (t + 1) * 32);
      }
    } else {
      // ---- materialize attn^{t+1} for the logits GEMM ----
      waitf(uflag + t * 32, 64);
      const int b2 = blk - 192;
      float* ad = attn_arr + ((size_t)t * NB + b2) * NH;
#pragma unroll
      for (int hh = 0; hh < 2; ++hh) {
        const int j = tid + hh * 256;
        ad[j] = tanhf(ldg_sys(u0 + (size_t)b2 * NH + j) +
                      ldg_sys(u1 + (size_t)b2 * NH + j) +
                      ldg_sys(cp + (size_t)b2 * NH + j));
      }
    }
  }
}

// ---------------------------------------------------------------------------
// Online single-pass log-softmax + argmax per row (1216 rows).
// ---------------------------------------------------------------------------
__global__ __launch_bounds__(256) void row_softmax_kernel(
    float* __restrict__ out, float* __restrict__ words)
{
  const int row = blockIdx.x;
  const int tid = threadIdx.x;
  float* p = out + (size_t)row * NV;
  __shared__ float sm[256];
  __shared__ int   si[256];
  __shared__ float ss[256];

  float mv = -INFINITY; int mi = 0; float s = 0.f;
  for (int i = tid; i < NV; i += 256) {
    float v = p[i];
    if (v > mv) {
      s = s * expf(mv - v) + 1.f;
      mv = v; mi = i;
    } else {
      s += expf(v - mv);
    }
  }
  sm[tid] = mv; si[tid] = mi; ss[tid] = s;
  __syncthreads();
  for (int off = 128; off >= 1; off >>= 1) {
    if (tid < off) {
      float m1 = sm[tid], m2 = sm[tid + off];
      float s1 = ss[tid], s2 = ss[tid + off];
      int   i1 = si[tid], i2 = si[tid + off];
      float M = fmaxf(m1, m2);
      ss[tid] = s1 * expf(m1 - M) + s2 * expf(m2 - M);
      if (m2 > m1 || (m2 == m1 && i2 < i1)) { sm[tid] = m2; si[tid] = i2; }
    }
    __syncthreads();
  }
  const float lse = sm[0] + logf(ss[0]);
  for (int i = tid; i < NV; i += 256) p[i] -= lse;
  if (tid == 0) words[row] = (float)si[0];
}

// init: zero gi partials (gi^0 attn-part == 0 since attn^0 == 0) and flags.
// System-scope stores so the coop kernel's bypassing reads see them even
// without relying on inter-kernel cache flush behavior.
__global__ __launch_bounds__(256) void init_kernel(
    float* __restrict__ giA2, int* __restrict__ flags)
{
  int i = blockIdx.x * 256 + threadIdx.x;
  if (i < 2 * NB * 1536) stg_sys(giA2 + i, 0.f);
  if (i < 4096)
    __hip_atomic_store(flags + i, 0, __ATOMIC_RELAXED, __HIP_MEMORY_SCOPE_SYSTEM);
}

extern "C" void kernel_launch(void* const* d_in, const int* in_sizes, int n_in,
                              void* d_out, int out_size, void* d_ws, size_t ws_size,
                              hipStream_t stream) {
  const int*   tgt       = (const int*)d_in[0];
  const int*   len_src   = (const int*)d_in[1];
  const float* enc_final = (const float*)d_in[3];
  const float* enc_out   = (const float*)d_in[4];
  const float* emb       = (const float*)d_in[6];
  const float* W_ih      = (const float*)d_in[7];
  const float* W_hh      = (const float*)d_in[8];
  const float* b_ih      = (const float*)d_in[9];
  const float* b_hh      = (const float*)d_in[10];
  const float* W_attn    = (const float*)d_in[11];
  const float* W_concat  = (const float*)d_in[12];
  const float* b_concat  = (const float*)d_in[13];
  const float* W_out     = (const float*)d_in[14];
  const float* b_out     = (const float*)d_in[15];
  float* out = (float*)d_out;

  // ---- workspace (18.35 MB, below previous 19.5 MB footprint) ----
  float* ws = (float*)d_ws;
  float* enc_proj = ws;                         // 64*64*512   = 2,097,152
  float* gi_emb   = ws + 2097152;               // 1216*1536   = 1,867,776
  float* attn_arr = ws + 3964928;               // 19*64*512   =   622,592

  // ---- scratch parked in the tail of d_out's logits region (free until
  //      logits_kernel runs; stream order guarantees no overlap in time) ----
  const size_t LOGF = (size_t)TSTEPS * NB * NV;        // 38,912,000 floats
  float* tail = out + (LOGF - 2723840);
  float* enc_proj2 = tail;                      // 2,097,152
  float* giA2  = enc_proj2 + 2097152;           //   196,608 (2 x 64x1536)
  float* ghA2  = giA2 + 196608;                 //   196,608
  float* ubuf  = ghA2 + 196608;                 //   131,072 [t&1][kh][64][512]
  float* ctxp  = ubuf + 131072;                 //    65,536 [t&1][64][512]
  float* hglob = ctxp + 65536;                  //    32,768
  int*   flags = (int*)(hglob + 32768);         //     4,096 ints

  init_kernel<<<768, 256, 0, stream>>>(giA2, flags);

  // enc_proj  = enc_out @ W_attn^T                 (4096 x 512, K=512)
  linear_kernel<<<dim3(4, 64), 256, 0, stream>>>(
      enc_out, 512, W_attn, 512, nullptr, enc_proj, 512, 512, 0);

  // enc_proj2 = enc_out @ W_concat[:,512:]^T       (ctx-half of concat, linear)
  linear_kernel<<<dim3(4, 64), 256, 0, stream>>>(
      enc_out, 512, W_concat + 512, 1024, nullptr, enc_proj2, 512, 512, 0);

  // gi_emb = emb[tgt] @ W_ih[:, :256]^T + b_ih     (1216 x 1536, K=256)
  emb_linear_kernel<<<dim3(12, 19), 256, 0, stream>>>(
      emb, tgt, W_ih, b_ih, gi_emb);

  // whole recurrence: one cooperative kernel, flag-chained (no grid.sync)
  void* kargs[] = {
    (void*)&gi_emb, (void*)&giA2, (void*)&ghA2, (void*)&hglob,
    (void*)&ubuf, (void*)&ctxp, (void*)&attn_arr,
    (void*)&enc_proj, (void*)&enc_proj2, (void*)&enc_final, (void*)&len_src,
    (void*)&W_ih, (void*)&W_hh, (void*)&b_hh, (void*)&W_concat,
    (void*)&b_concat, (void*)&flags
  };
  hipLaunchCooperativeKernel((const void*)recur_kernel, dim3(256), dim3(256),
                             kargs, 0, stream);

  // logits for all steps: (1216 x 512) @ (512 x 32000), XCD-swizzled
  logits_kernel<<<4864, 256, 0, stream>>>(attn_arr, W_out, b_out, out);

  // online log-softmax + argmax words
  row_softmax_kernel<<<TSTEPS * NB, 256, 0, stream>>>(out, out + LOGF);
}

// Round 2
// 2252.414 us; speedup vs baseline: 1.7117x; 1.0924x over previous
//
#include <hip/hip_runtime.h>
#include <math.h>

// Problem constants
#define TSTEPS 19   // T-1 decode steps
#define NB 64       // batch
#define NS 64       // src len
#define NT 20       // tgt len
#define NH 512      // hidden
#define NE 256      // emb dim
#define NV 32000    // vocab

// ---------------------------------------------------------------------------
// System-scope (cache-bypassing, MALL-coherent) helpers. All cross-block
// dataflow uses these; read-only weights use normal cached loads (L2-warm
// across all 19 steps since nothing ever flushes L2).
// Flags are WRITE-ONCE arrays (no atomic RMW -> no serialization at the
// coherence point); consumers poll 64 lanes wide with ballot.
// ---------------------------------------------------------------------------
__device__ __forceinline__ float ldg_sys(const float* p) {
  return __hip_atomic_load(p, __ATOMIC_RELAXED, __HIP_MEMORY_SCOPE_SYSTEM);
}
__device__ __forceinline__ void stg_sys(float* p, float v) {
  __hip_atomic_store(p, v, __ATOMIC_RELAXED, __HIP_MEMORY_SCOPE_SYSTEM);
}
__device__ __forceinline__ int ldi_sys(const int* p) {
  return __hip_atomic_load(p, __ATOMIC_RELAXED, __HIP_MEMORY_SCOPE_SYSTEM);
}
__device__ __forceinline__ void sti_sys(int* p, int v) {
  __hip_atomic_store(p, v, __ATOMIC_RELAXED, __HIP_MEMORY_SCOPE_SYSTEM);
}
__device__ __forceinline__ void vmfence() {
  asm volatile("s_waitcnt vmcnt(0)" ::: "memory");
}
// all data stores drained (per-wave), block barrier, then tid0 sets flag=1
__device__ __forceinline__ void flag_publish(int* f) {
  vmfence();
  __syncthreads();
  if (threadIdx.x == 0) sti_sys(f, 1);
  asm volatile("" ::: "memory");
}
// wave0 polls n write-once flags (n <= 192), ballot-combined; others park at
// the barrier. Detection lag ~ one uncached load RT + s_sleep(1).
__device__ __forceinline__ void wait_n(const int* f, int n) {
  if (threadIdx.x < 64) {
    for (;;) {
      int ok = 1;
      for (int i = threadIdx.x; i < n; i += 64) ok &= ldi_sys(f + i);
      if (__all(ok)) break;
      __builtin_amdgcn_s_sleep(1);
    }
  }
  __syncthreads();
  asm volatile("" ::: "memory");
}

// ---------------------------------------------------------------------------
// Generic fp32 linear: C[M,N] = A[M,K] @ W[N,K]^T (+bias). BM=64, BN=128,
// BK=16; 256 threads; 4x8 per thread. (enc_proj and enc_proj2)
// ---------------------------------------------------------------------------
__global__ __launch_bounds__(256) void linear_kernel(
    const float* __restrict__ A, int lda,
    const float* __restrict__ W, int ldw,
    const float* __restrict__ bias,
    float* __restrict__ C, int ldc,
    int K, int act)
{
  __shared__ float As[16][68];
  __shared__ float Ws[16][132];
  const int tid = threadIdx.x;
  const int m0 = blockIdx.y * 64;
  const int n0 = blockIdx.x * 128;
  const int lr = tid >> 2;
  const int lc = (tid & 3) << 2;
  const int tm = tid & 15;
  const int tn = tid >> 4;

  float acc[4][8];
#pragma unroll
  for (int i = 0; i < 4; ++i)
#pragma unroll
    for (int j = 0; j < 8; ++j) acc[i][j] = 0.f;

  const float* Ar  = A + (size_t)(m0 + lr) * lda + lc;
  const float* Wr0 = W + (size_t)(n0 + lr) * ldw + lc;
  const float* Wr1 = W + (size_t)(n0 + 64 + lr) * ldw + lc;

  for (int kk = 0; kk < K; kk += 16) {
    float4 av = *(const float4*)(Ar + kk);
    float4 w0 = *(const float4*)(Wr0 + kk);
    float4 w1 = *(const float4*)(Wr1 + kk);
    As[lc+0][lr] = av.x; As[lc+1][lr] = av.y; As[lc+2][lr] = av.z; As[lc+3][lr] = av.w;
    Ws[lc+0][lr] = w0.x; Ws[lc+1][lr] = w0.y; Ws[lc+2][lr] = w0.z; Ws[lc+3][lr] = w0.w;
    Ws[lc+0][64+lr] = w1.x; Ws[lc+1][64+lr] = w1.y; Ws[lc+2][64+lr] = w1.z; Ws[lc+3][64+lr] = w1.w;
    __syncthreads();
#pragma unroll
    for (int k = 0; k < 16; ++k) {
      float4 a4 = *(const float4*)&As[k][tm * 4];
      float4 b4 = *(const float4*)&Ws[k][tn * 8];
      float4 b5 = *(const float4*)&Ws[k][tn * 8 + 4];
      float a[4] = {a4.x, a4.y, a4.z, a4.w};
      float b[8] = {b4.x, b4.y, b4.z, b4.w, b5.x, b5.y, b5.z, b5.w};
#pragma unroll
      for (int i = 0; i < 4; ++i)
#pragma unroll
        for (int j = 0; j < 8; ++j)
          acc[i][j] = fmaf(a[i], b[j], acc[i][j]);
    }
    __syncthreads();
  }

#pragma unroll
  for (int i = 0; i < 4; ++i) {
    int m = m0 + tm * 4 + i;
    float* crow = C + (size_t)m * ldc + n0 + tn * 8;
    float vv[8];
#pragma unroll
    for (int j = 0; j < 8; ++j) {
      float v = acc[i][j];
      if (bias) v += bias[n0 + tn * 8 + j];
      if (act == 1) v = tanhf(v);
      vv[j] = v;
    }
    *(float4*)(crow)     = make_float4(vv[0], vv[1], vv[2], vv[3]);
    *(float4*)(crow + 4) = make_float4(vv[4], vv[5], vv[6], vv[7]);
  }
}

// ---------------------------------------------------------------------------
// gi_emb[t*64+b][:] = emb[tgt[b][t]] @ W_ih[:, :256]^T + b_ih   (1216 x 1536)
// ---------------------------------------------------------------------------
__global__ __launch_bounds__(256) void emb_linear_kernel(
    const float* __restrict__ emb, const int* __restrict__ tgt,
    const float* __restrict__ W_ih, const float* __restrict__ b_ih,
    float* __restrict__ C)
{
  __shared__ float As[16][68];
  __shared__ float Ws[16][132];
  const int tid = threadIdx.x;
  const int m0 = blockIdx.y * 64;
  const int n0 = blockIdx.x * 128;
  const int lr = tid >> 2;
  const int lc = (tid & 3) << 2;
  const int tm = tid & 15;
  const int tn = tid >> 4;

  float acc[4][8];
#pragma unroll
  for (int i = 0; i < 4; ++i)
#pragma unroll
    for (int j = 0; j < 8; ++j) acc[i][j] = 0.f;

  const int row = m0 + lr;                 // row = t*64 + b
  const int tok = tgt[(row & 63) * NT + (row >> 6)];
  const float* Ar  = emb + (size_t)tok * NE + lc;
  const float* Wr0 = W_ih + (size_t)(n0 + lr) * 768 + lc;
  const float* Wr1 = W_ih + (size_t)(n0 + 64 + lr) * 768 + lc;

  for (int kk = 0; kk < NE; kk += 16) {
    float4 av = *(const float4*)(Ar + kk);
    float4 w0 = *(const float4*)(Wr0 + kk);
    float4 w1 = *(const float4*)(Wr1 + kk);
    As[lc+0][lr] = av.x; As[lc+1][lr] = av.y; As[lc+2][lr] = av.z; As[lc+3][lr] = av.w;
    Ws[lc+0][lr] = w0.x; Ws[lc+1][lr] = w0.y; Ws[lc+2][lr] = w0.z; Ws[lc+3][lr] = w0.w;
    Ws[lc+0][64+lr] = w1.x; Ws[lc+1][64+lr] = w1.y; Ws[lc+2][64+lr] = w1.z; Ws[lc+3][64+lr] = w1.w;
    __syncthreads();
#pragma unroll
    for (int k = 0; k < 16; ++k) {
      float4 a4 = *(const float4*)&As[k][tm * 4];
      float4 b4 = *(const float4*)&Ws[k][tn * 8];
      float4 b5 = *(const float4*)&Ws[k][tn * 8 + 4];
      float a[4] = {a4.x, a4.y, a4.z, a4.w};
      float b[8] = {b4.x, b4.y, b4.z, b4.w, b5.x, b5.y, b5.z, b5.w};
#pragma unroll
      for (int i = 0; i < 4; ++i)
#pragma unroll
        for (int j = 0; j < 8; ++j)
          acc[i][j] = fmaf(a[i], b[j], acc[i][j]);
    }
    __syncthreads();
  }

#pragma unroll
  for (int i = 0; i < 4; ++i) {
    int m = m0 + tm * 4 + i;
    float* crow = C + (size_t)m * 1536 + n0 + tn * 8;
    float vv[8];
#pragma unroll
    for (int j = 0; j < 8; ++j) vv[j] = acc[i][j] + b_ih[n0 + tn * 8 + j];
    *(float4*)(crow)     = make_float4(vv[0], vv[1], vv[2], vv[3]);
    *(float4*)(crow + 4) = make_float4(vv[4], vv[5], vv[6], vv[7]);
  }
}

// ---------------------------------------------------------------------------
// Logits GEMM with XCD-ownership swizzle. C[1216,32000] = A @ W_out^T + b_out.
// ---------------------------------------------------------------------------
__global__ __launch_bounds__(256) void logits_kernel(
    const float* __restrict__ A, const float* __restrict__ W,
    const float* __restrict__ bias, float* __restrict__ C)
{
  const int bfl = blockIdx.x;
  const int xcd = bfl & 7;
  const int jj = bfl >> 3;
  const int mt = jj % 19;
  const int nt = xcd * 32 + jj / 19;
  if (nt >= 250) return;          // uniform whole-block exit before barriers
  const int m0 = mt * 64;
  const int n0 = nt * 128;

  __shared__ float As[16][68];
  __shared__ float Ws[16][132];
  const int tid = threadIdx.x;
  const int lr = tid >> 2;
  const int lc = (tid & 3) << 2;
  const int tm = tid & 15;
  const int tn = tid >> 4;

  float acc[4][8];
#pragma unroll
  for (int i = 0; i < 4; ++i)
#pragma unroll
    for (int j = 0; j < 8; ++j) acc[i][j] = 0.f;

  const float* Ar  = A + (size_t)(m0 + lr) * NH + lc;
  const float* Wr0 = W + (size_t)(n0 + lr) * NH + lc;
  const float* Wr1 = W + (size_t)(n0 + 64 + lr) * NH + lc;

  for (int kk = 0; kk < NH; kk += 16) {
    float4 av = *(const float4*)(Ar + kk);
    float4 w0 = *(const float4*)(Wr0 + kk);
    float4 w1 = *(const float4*)(Wr1 + kk);
    As[lc+0][lr] = av.x; As[lc+1][lr] = av.y; As[lc+2][lr] = av.z; As[lc+3][lr] = av.w;
    Ws[lc+0][lr] = w0.x; Ws[lc+1][lr] = w0.y; Ws[lc+2][lr] = w0.z; Ws[lc+3][lr] = w0.w;
    Ws[lc+0][64+lr] = w1.x; Ws[lc+1][64+lr] = w1.y; Ws[lc+2][64+lr] = w1.z; Ws[lc+3][64+lr] = w1.w;
    __syncthreads();
#pragma unroll
    for (int k = 0; k < 16; ++k) {
      float4 a4 = *(const float4*)&As[k][tm * 4];
      float4 b4 = *(const float4*)&Ws[k][tn * 8];
      float4 b5 = *(const float4*)&Ws[k][tn * 8 + 4];
      float a[4] = {a4.x, a4.y, a4.z, a4.w};
      float b[8] = {b4.x, b4.y, b4.z, b4.w, b5.x, b5.y, b5.z, b5.w};
#pragma unroll
      for (int i = 0; i < 4; ++i)
#pragma unroll
        for (int j = 0; j < 8; ++j)
          acc[i][j] = fmaf(a[i], b[j], acc[i][j]);
    }
    __syncthreads();
  }

#pragma unroll
  for (int i = 0; i < 4; ++i) {
    int m = m0 + tm * 4 + i;
    float* crow = C + (size_t)m * NV + n0 + tn * 8;
    float vv[8];
#pragma unroll
    for (int j = 0; j < 8; ++j) vv[j] = acc[i][j] + bias[n0 + tn * 8 + j];
    *(float4*)(crow)     = make_float4(vv[0], vv[1], vv[2], vv[3]);
    *(float4*)(crow + 4) = make_float4(vv[4], vv[5], vv[6], vv[7]);
  }
}

// ---------------------------------------------------------------------------
// Helper 64m x 16n x 256k GEMM tile (one split-K half). A is [64][NH].
// SYSA=0: cached float4 A loads (read-only input). SYSA=1: system-scope
// scalar loads, coalesced (16-lane groups cover 256B of one row).
// LDS staging via ds_write_b128 (4 stores/thread/chunk, near-floor banks).
// C written as 4 scalar sys stores at [m][n0+nq*4..+3], ldc=1536.
// ---------------------------------------------------------------------------
template <int SYSA>
__device__ __forceinline__ void gemm_tile2(
    const float* __restrict__ Asrc, const float* __restrict__ W, int ldw,
    float* __restrict__ Cdst, int n0, int k0,
    float (*As)[68], float (*Ws)[68])
{
  const int tid = threadIdx.x;
  const int l = tid & 63, w = tid >> 6;
  const int m = l, nq = w;                       // compute mapping
  const int wn = tid >> 4, wc = (tid & 15) << 2; // W staging
  const int q4 = (l & 15) << 2;                  // A staging col (floats)
  float acc[4] = {0.f, 0.f, 0.f, 0.f};
  for (int kk = 0; kk < 256; kk += 64) {
    const int kb = k0 + kk;
#pragma unroll
    for (int i = 0; i < 4; ++i) {
      const int mi = 16 * w + 4 * i + (l >> 4);
      const float* src = Asrc + (size_t)mi * NH + kb + q4;
      float4 v;
      if (SYSA) {
        v.x = ldg_sys(src); v.y = ldg_sys(src + 1);
        v.z = ldg_sys(src + 2); v.w = ldg_sys(src + 3);
      } else {
        v = *(const float4*)src;
      }
      *(float4*)&As[mi][q4] = v;
    }
    *(float4*)&Ws[wn][wc] = *(const float4*)(W + (size_t)(n0 + wn) * ldw + kb + wc);
    __syncthreads();
#pragma unroll
    for (int q = 0; q < 16; ++q) {
      float4 a4 = *(const float4*)&As[m][q * 4];
#pragma unroll
      for (int j = 0; j < 4; ++j) {
        float4 w4 = *(const float4*)&Ws[nq * 4 + j][q * 4];
        acc[j] = fmaf(a4.x, w4.x, acc[j]);
        acc[j] = fmaf(a4.y, w4.y, acc[j]);
        acc[j] = fmaf(a4.z, w4.z, acc[j]);
        acc[j] = fmaf(a4.w, w4.w, acc[j]);
      }
    }
    __syncthreads();
  }
#pragma unroll
  for (int j = 0; j < 4; ++j)
    stg_sys(Cdst + (size_t)m * 1536 + n0 + nq * 4 + j, acc[j]);
}

// ---------------------------------------------------------------------------
// Recurrence, short-chain version. 256 blocks x 256 threads, cooperative
// (co-residency only; no grid.sync, no atomics, no L2 maintenance).
//
// Rows (blk<64, b=blk): per step t:
//   wait ghdone[t](192) [+ gidone[t](192) if t>0]
//   gates -> h^{t+1} (LDS + sys hglob) -> flag hdone[t][b]
//   scores -> softmax -> ctx-part (enc_proj2 trick, in registers)
//   u-matvec (W_concat h-half, 1MB cached L2-warm, own row only -> NO waits)
//   attn^{t+1} = tanh(u + ctxp) -> attn_arr[t] (sys) -> flag adone[t][b]
// Helpers (blk 64..255, hj=blk-64 -> n0=(hj>>1)*16, kh=hj&1):
//   prologue: ghP[0] = enc_final @ W_hh^T (cached) -> ghdone[0]
//   per t<18: wait hdone[t] -> ghP[t+1] = h @ W_hh^T -> ghdone[t+1]
//             wait adone[t] -> giP[t+1] = attn @ W_ihh^T -> gidone[t+1]
// gi at t=0 is exactly 0 (attn^0 == 0): gates skip it; no zero-init needed.
// Chain/step: gates -> (attn path || gh gemm) -> gi gemm. 2 productive hops.
// ---------------------------------------------------------------------------
__global__ __launch_bounds__(256) void recur_kernel(
    const float* __restrict__ gi_emb, float* __restrict__ giA2,
    float* __restrict__ ghA2, float* __restrict__ hglob,
    float* __restrict__ attn_arr, const float* __restrict__ enc_proj,
    const float* __restrict__ enc_proj2, const float* __restrict__ enc_final,
    const int* __restrict__ len_src, const float* __restrict__ W_ih,
    const float* __restrict__ W_hh, const float* __restrict__ b_hh,
    const float* __restrict__ W_concat, const float* __restrict__ b_concat,
    int* __restrict__ flags)
{
  const int blk = blockIdx.x;
  const int tid = threadIdx.x;
  __shared__ float As[64][68];
  __shared__ float Ws[16][68];
  __shared__ float hstate[NH];
  __shared__ float scs[NS];
  __shared__ float aw[NS];

  int* ghdone = flags;           // [t*192 + hj], t = 0..18
  int* gidone = flags + 4096;    // [t*192 + hj], t = 1..18
  int* hdone  = flags + 8192;    // [t*64 + b],   t = 0..18
  int* adone  = flags + 10240;   // [t*64 + b],   t = 0..18

  if (blk >= 64) {
    // ---------------- helpers ----------------
    const int hj = blk - 64;
    const int n0 = (hj >> 1) * 16;
    const int kh = hj & 1;
    const int k0 = kh * 256;
    float* ghD = ghA2 + kh * 98304;
    float* giD = giA2 + kh * 98304;
    // prologue: ghP[0] from enc_final (read-only input, cached)
    gemm_tile2<0>(enc_final, W_hh, NH, ghD, n0, k0, As, Ws);
    flag_publish(ghdone + hj);
    for (int t = 0; t + 1 < TSTEPS; ++t) {
      wait_n(hdone + t * 64, 64);
      gemm_tile2<1>(hglob, W_hh, NH, ghD, n0, k0, As, Ws);
      flag_publish(ghdone + (t + 1) * 192 + hj);
      wait_n(adone + t * 64, 64);
      gemm_tile2<1>(attn_arr + (size_t)t * NB * NH, W_ih + NE, NE + NH,
                    giD, n0, k0, As, Ws);
      flag_publish(gidone + (t + 1) * 192 + hj);
    }
    return;
  }

  // ---------------- rows ----------------
  const int b = blk;
  hstate[tid]       = enc_final[(size_t)b * NH + tid];
  hstate[tid + 256] = enc_final[(size_t)b * NH + tid + 256];
  __syncthreads();
  const int mylen = len_src[b];

  for (int t = 0; t < TSTEPS; ++t) {
    wait_n(ghdone + t * 192, 192);
    if (t > 0) wait_n(gidone + t * 192, 192);

    // ---- GRU gates: h^{t+1} ----
    const float* ge = gi_emb + (size_t)(t * NB + b) * 1536;
#pragma unroll
    for (int hh = 0; hh < 2; ++hh) {
      const int j = tid + hh * 256;
      const size_t base = (size_t)b * 1536 + j;
      float gr = ge[j];
      float gz = ge[512 + j];
      float gn = ge[1024 + j];
      if (t > 0) {
        gr += ldg_sys(giA2 + base)        + ldg_sys(giA2 + 98304 + base);
        gz += ldg_sys(giA2 + base + 512)  + ldg_sys(giA2 + 98304 + base + 512);
        gn += ldg_sys(giA2 + base + 1024) + ldg_sys(giA2 + 98304 + base + 1024);
      }
      float hr = b_hh[j]        + ldg_sys(ghA2 + base)        + ldg_sys(ghA2 + 98304 + base);
      float hz = b_hh[512 + j]  + ldg_sys(ghA2 + base + 512)  + ldg_sys(ghA2 + 98304 + base + 512);
      float hn = b_hh[1024 + j] + ldg_sys(ghA2 + base + 1024) + ldg_sys(ghA2 + 98304 + base + 1024);
      float r = 1.f / (1.f + expf(-(gr + hr)));
      float z = 1.f / (1.f + expf(-(gz + hz)));
      float n = tanhf(gn + r * hn);
      float h = (1.f - z) * n + z * hstate[j];
      hstate[j] = h;
      stg_sys(hglob + (size_t)b * NH + j, h);
    }
    vmfence();
    __syncthreads();               // also orders hstate for the scores below
    if (tid == 0) sti_sys(hdone + t * 64 + b, 1);

    // ---- attention scores (own row; cached enc_proj, L2-warm) ----
    {
      const int s = tid >> 2, sub = tid & 3;
      const float* ep = enc_proj + ((size_t)s * NB + b) * NH + sub * 4;
      float acc = 0.f;
#pragma unroll 8
      for (int i = 0; i < 32; ++i) {
        float4 e4 = *(const float4*)(ep + i * 16);
        float4 h4 = *(const float4*)&hstate[i * 16 + sub * 4];
        acc = fmaf(e4.x, h4.x, acc); acc = fmaf(e4.y, h4.y, acc);
        acc = fmaf(e4.z, h4.z, acc); acc = fmaf(e4.w, h4.w, acc);
      }
      acc += __shfl_xor(acc, 1);
      acc += __shfl_xor(acc, 2);
      if (sub == 0) scs[s] = acc;
    }
    __syncthreads();
    // ---- masked softmax (wave 0) ----
    if (tid < 64) {
      float v = (tid < mylen) ? scs[tid] : -1e9f;
      float mm = v;
      for (int off = 32; off >= 1; off >>= 1) mm = fmaxf(mm, __shfl_xor(mm, off));
      float e = expf(v - mm);
      float ssum = e;
      for (int off = 32; off >= 1; off >>= 1) ssum += __shfl_xor(ssum, off);
      aw[tid] = e / ssum;
    }
    __syncthreads();
    // ---- ctx-part in registers: sum_s aw[s]*enc_proj2[s][b][:] ----
    float c0 = 0.f, c1 = 0.f;
#pragma unroll 4
    for (int s2 = 0; s2 < NS; ++s2) {
      const float w = aw[s2];
      const float* e2 = enc_proj2 + ((size_t)s2 * NB + b) * NH;
      c0 = fmaf(w, e2[tid], c0);
      c1 = fmaf(w, e2[tid + 256], c1);
    }
    // ---- u-matvec (own row, cached W_concat h-half) + attn store ----
    float* at = attn_arr + ((size_t)t * NB + b) * NH;
#pragma unroll
    for (int h2 = 0; h2 < 2; ++h2) {
      const int n = tid + h2 * 256;
      const float* wr = W_concat + (size_t)n * (2 * NH);
      float acc = 0.f;
      for (int k = 0; k < NH; k += 4) {
        float4 w4 = *(const float4*)(wr + k);
        acc = fmaf(w4.x, hstate[k],     acc);
        acc = fmaf(w4.y, hstate[k + 1], acc);
        acc = fmaf(w4.z, hstate[k + 2], acc);
        acc = fmaf(w4.w, hstate[k + 3], acc);
      }
      acc += b_concat[n] + (h2 ? c1 : c0);
      stg_sys(at + n, tanhf(acc));
    }
    vmfence();
    __syncthreads();
    if (tid == 0) sti_sys(adone + t * 64 + b, 1);
  }
}

// ---------------------------------------------------------------------------
// Online single-pass log-softmax + argmax per row (1216 rows).
// ---------------------------------------------------------------------------
__global__ __launch_bounds__(256) void row_softmax_kernel(
    float* __restrict__ out, float* __restrict__ words)
{
  const int row = blockIdx.x;
  const int tid = threadIdx.x;
  float* p = out + (size_t)row * NV;
  __shared__ float sm[256];
  __shared__ int   si[256];
  __shared__ float ss[256];

  float mv = -INFINITY; int mi = 0; float s = 0.f;
  for (int i = tid; i < NV; i += 256) {
    float v = p[i];
    if (v > mv) {
      s = s * expf(mv - v) + 1.f;
      mv = v; mi = i;
    } else {
      s += expf(v - mv);
    }
  }
  sm[tid] = mv; si[tid] = mi; ss[tid] = s;
  __syncthreads();
  for (int off = 128; off >= 1; off >>= 1) {
    if (tid < off) {
      float m1 = sm[tid], m2 = sm[tid + off];
      float s1 = ss[tid], s2 = ss[tid + off];
      int   i1 = si[tid], i2 = si[tid + off];
      float M = fmaxf(m1, m2);
      ss[tid] = s1 * expf(m1 - M) + s2 * expf(m2 - M);
      if (m2 > m1 || (m2 == m1 && i2 < i1)) { sm[tid] = m2; si[tid] = i2; }
    }
    __syncthreads();
  }
  const float lse = sm[0] + logf(ss[0]);
  for (int i = tid; i < NV; i += 256) p[i] -= lse;
  if (tid == 0) words[row] = (float)si[0];
}

// init: zero the write-once flag arrays (re-zeroed every launch, stream-order
// before the cooperative kernel).
__global__ __launch_bounds__(256) void init_kernel(int* __restrict__ flags)
{
  int i = blockIdx.x * 256 + threadIdx.x;
  if (i < 12288)
    __hip_atomic_store(flags + i, 0, __ATOMIC_RELAXED, __HIP_MEMORY_SCOPE_SYSTEM);
}

extern "C" void kernel_launch(void* const* d_in, const int* in_sizes, int n_in,
                              void* d_out, int out_size, void* d_ws, size_t ws_size,
                              hipStream_t stream) {
  const int*   tgt       = (const int*)d_in[0];
  const int*   len_src   = (const int*)d_in[1];
  const float* enc_final = (const float*)d_in[3];
  const float* enc_out   = (const float*)d_in[4];
  const float* emb       = (const float*)d_in[6];
  const float* W_ih      = (const float*)d_in[7];
  const float* W_hh      = (const float*)d_in[8];
  const float* b_ih      = (const float*)d_in[9];
  const float* b_hh      = (const float*)d_in[10];
  const float* W_attn    = (const float*)d_in[11];
  const float* W_concat  = (const float*)d_in[12];
  const float* b_concat  = (const float*)d_in[13];
  const float* W_out     = (const float*)d_in[14];
  const float* b_out     = (const float*)d_in[15];
  float* out = (float*)d_out;

  // ---- workspace ----
  float* ws = (float*)d_ws;
  float* enc_proj = ws;                         // 64*64*512   = 2,097,152
  float* gi_emb   = ws + 2097152;               // 1216*1536   = 1,867,776
  float* attn_arr = ws + 3964928;               // 19*64*512   =   622,592

  // ---- scratch parked in the tail of d_out's logits region (free until
  //      logits_kernel runs; stream order guarantees no overlap in time) ----
  const size_t LOGF = (size_t)TSTEPS * NB * NV;        // 38,912,000 floats
  float* tail = out + (LOGF - 2560000);
  float* enc_proj2 = tail;                      // 2,097,152
  float* giA2  = enc_proj2 + 2097152;           //   196,608 (2 x 64x1536)
  float* ghA2  = giA2 + 196608;                 //   196,608
  float* hglob = ghA2 + 196608;                 //    32,768
  int*   flags = (int*)(hglob + 32768);         //    12,288 ints

  init_kernel<<<48, 256, 0, stream>>>(flags);

  // enc_proj  = enc_out @ W_attn^T                 (4096 x 512, K=512)
  linear_kernel<<<dim3(4, 64), 256, 0, stream>>>(
      enc_out, 512, W_attn, 512, nullptr, enc_proj, 512, 512, 0);

  // enc_proj2 = enc_out @ W_concat[:,512:]^T       (ctx-half of concat, linear)
  linear_kernel<<<dim3(4, 64), 256, 0, stream>>>(
      enc_out, 512, W_concat + 512, 1024, nullptr, enc_proj2, 512, 512, 0);

  // gi_emb = emb[tgt] @ W_ih[:, :256]^T + b_ih     (1216 x 1536, K=256)
  emb_linear_kernel<<<dim3(12, 19), 256, 0, stream>>>(
      emb, tgt, W_ih, b_ih, gi_emb);

  // whole recurrence: one cooperative kernel, short flag chain
  void* kargs[] = {
    (void*)&gi_emb, (void*)&giA2, (void*)&ghA2, (void*)&hglob,
    (void*)&attn_arr, (void*)&enc_proj, (void*)&enc_proj2, (void*)&enc_final,
    (void*)&len_src, (void*)&W_ih, (void*)&W_hh, (void*)&b_hh,
    (void*)&W_concat, (void*)&b_concat, (void*)&flags
  };
  hipLaunchCooperativeKernel((const void*)recur_kernel, dim3(256), dim3(256),
                             kargs, 0, stream);

  // logits for all steps: (1216 x 512) @ (512 x 32000), XCD-swizzled
  logits_kernel<<<4864, 256, 0, stream>>>(attn_arr, W_out, b_out, out);

  // online log-softmax + argmax words
  row_softmax_kernel<<<TSTEPS * NB, 256, 0, stream>>>(
      out, out + LOGF);
}

// Round 3
// 2002.513 us; speedup vs baseline: 1.9253x; 1.1248x over previous
//
#include <hip/hip_runtime.h>
#include <math.h>

// Problem constants
#define TSTEPS 19   // T-1 decode steps
#define NB 64       // batch
#define NS 64       // src len
#define NT 20       // tgt len
#define NH 512      // hidden
#define NE 256      // emb dim
#define NV 32000    // vocab

typedef float f32x4 __attribute__((ext_vector_type(4)));

// ---------------------------------------------------------------------------
// Cross-block dataflow primitives. Data: batched inline-asm dwordx4 with
// sc0 sc1 (bypass L1/L2 -> MALL-coherent, no cache maintenance ever needed;
// read-only weights stay L2-warm across all 19 steps). The waitcnt lives in
// the SAME asm block as its loads (no hoist hazard). Flags: write-once int
// arrays, scalar system-scope atomics (few per step).
// ---------------------------------------------------------------------------
__device__ __forceinline__ int ldi_sys(const int* p) {
  return __hip_atomic_load(p, __ATOMIC_RELAXED, __HIP_MEMORY_SCOPE_SYSTEM);
}
__device__ __forceinline__ void sti_sys(int* p, int v) {
  __hip_atomic_store(p, v, __ATOMIC_RELAXED, __HIP_MEMORY_SCOPE_SYSTEM);
}
__device__ __forceinline__ void vmfence() {
  asm volatile("s_waitcnt vmcnt(0)" ::: "memory");
}
__device__ __forceinline__ void stg4(float* p, f32x4 v) {
  asm volatile("global_store_dwordx4 %0, %1, off sc0 sc1" :: "v"(p), "v"(v) : "memory");
}
// all data stores drained (per-wave), block barrier, then tid0 sets flag=1
__device__ __forceinline__ void flag_publish(int* f) {
  vmfence();
  __syncthreads();
  if (threadIdx.x == 0) sti_sys(f, 1);
  asm volatile("" ::: "memory");
}
// wave0 polls n write-once flags, ballot-combined; others park at barrier.
__device__ __forceinline__ void wait_n(const int* f, int n) {
  if (threadIdx.x < 64) {
    for (;;) {
      int ok = 1;
      for (int i = threadIdx.x; i < n; i += 64) ok &= ldi_sys(f + i);
      if (__all(ok)) break;
      __builtin_amdgcn_s_sleep(1);
    }
  }
  __syncthreads();
  asm volatile("" ::: "memory");
}

// ---------------------------------------------------------------------------
// Generic fp32 linear: C[M,N] = A[M,K] @ W[N,K]^T (+bias). BM=64, BN=128.
// ---------------------------------------------------------------------------
__global__ __launch_bounds__(256) void linear_kernel(
    const float* __restrict__ A, int lda,
    const float* __restrict__ W, int ldw,
    const float* __restrict__ bias,
    float* __restrict__ C, int ldc,
    int K, int act)
{
  __shared__ float As[16][68];
  __shared__ float Ws[16][132];
  const int tid = threadIdx.x;
  const int m0 = blockIdx.y * 64;
  const int n0 = blockIdx.x * 128;
  const int lr = tid >> 2;
  const int lc = (tid & 3) << 2;
  const int tm = tid & 15;
  const int tn = tid >> 4;

  float acc[4][8];
#pragma unroll
  for (int i = 0; i < 4; ++i)
#pragma unroll
    for (int j = 0; j < 8; ++j) acc[i][j] = 0.f;

  const float* Ar  = A + (size_t)(m0 + lr) * lda + lc;
  const float* Wr0 = W + (size_t)(n0 + lr) * ldw + lc;
  const float* Wr1 = W + (size_t)(n0 + 64 + lr) * ldw + lc;

  for (int kk = 0; kk < K; kk += 16) {
    float4 av = *(const float4*)(Ar + kk);
    float4 w0 = *(const float4*)(Wr0 + kk);
    float4 w1 = *(const float4*)(Wr1 + kk);
    As[lc+0][lr] = av.x; As[lc+1][lr] = av.y; As[lc+2][lr] = av.z; As[lc+3][lr] = av.w;
    Ws[lc+0][lr] = w0.x; Ws[lc+1][lr] = w0.y; Ws[lc+2][lr] = w0.z; Ws[lc+3][lr] = w0.w;
    Ws[lc+0][64+lr] = w1.x; Ws[lc+1][64+lr] = w1.y; Ws[lc+2][64+lr] = w1.z; Ws[lc+3][64+lr] = w1.w;
    __syncthreads();
#pragma unroll
    for (int k = 0; k < 16; ++k) {
      float4 a4 = *(const float4*)&As[k][tm * 4];
      float4 b4 = *(const float4*)&Ws[k][tn * 8];
      float4 b5 = *(const float4*)&Ws[k][tn * 8 + 4];
      float a[4] = {a4.x, a4.y, a4.z, a4.w};
      float b[8] = {b4.x, b4.y, b4.z, b4.w, b5.x, b5.y, b5.z, b5.w};
#pragma unroll
      for (int i = 0; i < 4; ++i)
#pragma unroll
        for (int j = 0; j < 8; ++j)
          acc[i][j] = fmaf(a[i], b[j], acc[i][j]);
    }
    __syncthreads();
  }

#pragma unroll
  for (int i = 0; i < 4; ++i) {
    int m = m0 + tm * 4 + i;
    float* crow = C + (size_t)m * ldc + n0 + tn * 8;
    float vv[8];
#pragma unroll
    for (int j = 0; j < 8; ++j) {
      float v = acc[i][j];
      if (bias) v += bias[n0 + tn * 8 + j];
      if (act == 1) v = tanhf(v);
      vv[j] = v;
    }
    *(float4*)(crow)     = make_float4(vv[0], vv[1], vv[2], vv[3]);
    *(float4*)(crow + 4) = make_float4(vv[4], vv[5], vv[6], vv[7]);
  }
}

// ---------------------------------------------------------------------------
// gi_emb[t*64+b][:] = emb[tgt[b][t]] @ W_ih[:, :256]^T + b_ih   (1216 x 1536)
// ---------------------------------------------------------------------------
__global__ __launch_bounds__(256) void emb_linear_kernel(
    const float* __restrict__ emb, const int* __restrict__ tgt,
    const float* __restrict__ W_ih, const float* __restrict__ b_ih,
    float* __restrict__ C)
{
  __shared__ float As[16][68];
  __shared__ float Ws[16][132];
  const int tid = threadIdx.x;
  const int m0 = blockIdx.y * 64;
  const int n0 = blockIdx.x * 128;
  const int lr = tid >> 2;
  const int lc = (tid & 3) << 2;
  const int tm = tid & 15;
  const int tn = tid >> 4;

  float acc[4][8];
#pragma unroll
  for (int i = 0; i < 4; ++i)
#pragma unroll
    for (int j = 0; j < 8; ++j) acc[i][j] = 0.f;

  const int row = m0 + lr;                 // row = t*64 + b
  const int tok = tgt[(row & 63) * NT + (row >> 6)];
  const float* Ar  = emb + (size_t)tok * NE + lc;
  const float* Wr0 = W_ih + (size_t)(n0 + lr) * 768 + lc;
  const float* Wr1 = W_ih + (size_t)(n0 + 64 + lr) * 768 + lc;

  for (int kk = 0; kk < NE; kk += 16) {
    float4 av = *(const float4*)(Ar + kk);
    float4 w0 = *(const float4*)(Wr0 + kk);
    float4 w1 = *(const float4*)(Wr1 + kk);
    As[lc+0][lr] = av.x; As[lc+1][lr] = av.y; As[lc+2][lr] = av.z; As[lc+3][lr] = av.w;
    Ws[lc+0][lr] = w0.x; Ws[lc+1][lr] = w0.y; Ws[lc+2][lr] = w0.z; Ws[lc+3][lr] = w0.w;
    Ws[lc+0][64+lr] = w1.x; Ws[lc+1][64+lr] = w1.y; Ws[lc+2][64+lr] = w1.z; Ws[lc+3][64+lr] = w1.w;
    __syncthreads();
#pragma unroll
    for (int k = 0; k < 16; ++k) {
      float4 a4 = *(const float4*)&As[k][tm * 4];
      float4 b4 = *(const float4*)&Ws[k][tn * 8];
      float4 b5 = *(const float4*)&Ws[k][tn * 8 + 4];
      float a[4] = {a4.x, a4.y, a4.z, a4.w};
      float b[8] = {b4.x, b4.y, b4.z, b4.w, b5.x, b5.y, b5.z, b5.w};
#pragma unroll
      for (int i = 0; i < 4; ++i)
#pragma unroll
        for (int j = 0; j < 8; ++j)
          acc[i][j] = fmaf(a[i], b[j], acc[i][j]);
    }
    __syncthreads();
  }

#pragma unroll
  for (int i = 0; i < 4; ++i) {
    int m = m0 + tm * 4 + i;
    float* crow = C + (size_t)m * 1536 + n0 + tn * 8;
    float vv[8];
#pragma unroll
    for (int j = 0; j < 8; ++j) vv[j] = acc[i][j] + b_ih[n0 + tn * 8 + j];
    *(float4*)(crow)     = make_float4(vv[0], vv[1], vv[2], vv[3]);
    *(float4*)(crow + 4) = make_float4(vv[4], vv[5], vv[6], vv[7]);
  }
}

// ---------------------------------------------------------------------------
// Logits GEMM with XCD-ownership swizzle. C[1216,32000] = A @ W_out^T + b_out.
// ---------------------------------------------------------------------------
__global__ __launch_bounds__(256) void logits_kernel(
    const float* __restrict__ A, const float* __restrict__ W,
    const float* __restrict__ bias, float* __restrict__ C)
{
  const int bfl = blockIdx.x;
  const int xcd = bfl & 7;
  const int jj = bfl >> 3;
  const int mt = jj % 19;
  const int nt = xcd * 32 + jj / 19;
  if (nt >= 250) return;          // uniform whole-block exit before barriers
  const int m0 = mt * 64;
  const int n0 = nt * 128;

  __shared__ float As[16][68];
  __shared__ float Ws[16][132];
  const int tid = threadIdx.x;
  const int lr = tid >> 2;
  const int lc = (tid & 3) << 2;
  const int tm = tid & 15;
  const int tn = tid >> 4;

  float acc[4][8];
#pragma unroll
  for (int i = 0; i < 4; ++i)
#pragma unroll
    for (int j = 0; j < 8; ++j) acc[i][j] = 0.f;

  const float* Ar  = A + (size_t)(m0 + lr) * NH + lc;
  const float* Wr0 = W + (size_t)(n0 + lr) * NH + lc;
  const float* Wr1 = W + (size_t)(n0 + 64 + lr) * NH + lc;

  for (int kk = 0; kk < NH; kk += 16) {
    float4 av = *(const float4*)(Ar + kk);
    float4 w0 = *(const float4*)(Wr0 + kk);
    float4 w1 = *(const float4*)(Wr1 + kk);
    As[lc+0][lr] = av.x; As[lc+1][lr] = av.y; As[lc+2][lr] = av.z; As[lc+3][lr] = av.w;
    Ws[lc+0][lr] = w0.x; Ws[lc+1][lr] = w0.y; Ws[lc+2][lr] = w0.z; Ws[lc+3][lr] = w0.w;
    Ws[lc+0][64+lr] = w1.x; Ws[lc+1][64+lr] = w1.y; Ws[lc+2][64+lr] = w1.z; Ws[lc+3][64+lr] = w1.w;
    __syncthreads();
#pragma unroll
    for (int k = 0; k < 16; ++k) {
      float4 a4 = *(const float4*)&As[k][tm * 4];
      float4 b4 = *(const float4*)&Ws[k][tn * 8];
      float4 b5 = *(const float4*)&Ws[k][tn * 8 + 4];
      float a[4] = {a4.x, a4.y, a4.z, a4.w};
      float b[8] = {b4.x, b4.y, b4.z, b4.w, b5.x, b5.y, b5.z, b5.w};
#pragma unroll
      for (int i = 0; i < 4; ++i)
#pragma unroll
        for (int j = 0; j < 8; ++j)
          acc[i][j] = fmaf(a[i], b[j], acc[i][j]);
    }
    __syncthreads();
  }

#pragma unroll
  for (int i = 0; i < 4; ++i) {
    int m = m0 + tm * 4 + i;
    float* crow = C + (size_t)m * NV + n0 + tn * 8;
    float vv[8];
#pragma unroll
    for (int j = 0; j < 8; ++j) vv[j] = acc[i][j] + bias[n0 + tn * 8 + j];
    *(float4*)(crow)     = make_float4(vv[0], vv[1], vv[2], vv[3]);
    *(float4*)(crow + 4) = make_float4(vv[4], vv[5], vv[6], vv[7]);
  }
}

// ---------------------------------------------------------------------------
// Helper 64m x 32n x 256k GEMM (one split-K half). Whole A-slice (64x256)
// staged in ONE shot: 16 dwordx4/thread in two asm batches sharing a single
// vmcnt(0) -> one MALL round-trip. W staged cached (L2-warm). Thread frag:
// 2m x 4n (rows tm,tm+32 ; cols n0+tn*4..+3), 2048 fma. Partials stored as
// 2 bypassing dwordx4.
// ---------------------------------------------------------------------------
template <int SYSA>
__device__ __forceinline__ void gemm_helper(
    const float* __restrict__ Asrc, const float* __restrict__ W, int ldw,
    float* __restrict__ Cdst, int n0, int k0,
    float (*As)[260], float (*Ws)[260])
{
  const int tid = threadIdx.x;
  // ---- stage A: 64x256 floats = 4096 f32x4, 16 per thread ----
  if (SYSA) {
    const float* s[16];
#pragma unroll
    for (int i = 0; i < 16; ++i) {
      const int f = tid + (i << 8);
      s[i] = Asrc + (size_t)(f >> 6) * NH + k0 + ((f & 63) << 2);
    }
    f32x4 v0,v1,v2,v3,v4,v5,v6,v7,v8,v9,v10,v11,v12,v13,v14,v15;
    asm volatile(
      "global_load_dwordx4 %0, %8, off sc0 sc1\n\t"
      "global_load_dwordx4 %1, %9, off sc0 sc1\n\t"
      "global_load_dwordx4 %2, %10, off sc0 sc1\n\t"
      "global_load_dwordx4 %3, %11, off sc0 sc1\n\t"
      "global_load_dwordx4 %4, %12, off sc0 sc1\n\t"
      "global_load_dwordx4 %5, %13, off sc0 sc1\n\t"
      "global_load_dwordx4 %6, %14, off sc0 sc1\n\t"
      "global_load_dwordx4 %7, %15, off sc0 sc1"
      : "=&v"(v0),"=&v"(v1),"=&v"(v2),"=&v"(v3),
        "=&v"(v4),"=&v"(v5),"=&v"(v6),"=&v"(v7)
      : "v"(s[0]),"v"(s[1]),"v"(s[2]),"v"(s[3]),
        "v"(s[4]),"v"(s[5]),"v"(s[6]),"v"(s[7])
      : "memory");
    asm volatile(
      "global_load_dwordx4 %0, %8, off sc0 sc1\n\t"
      "global_load_dwordx4 %1, %9, off sc0 sc1\n\t"
      "global_load_dwordx4 %2, %10, off sc0 sc1\n\t"
      "global_load_dwordx4 %3, %11, off sc0 sc1\n\t"
      "global_load_dwordx4 %4, %12, off sc0 sc1\n\t"
      "global_load_dwordx4 %5, %13, off sc0 sc1\n\t"
      "global_load_dwordx4 %6, %14, off sc0 sc1\n\t"
      "global_load_dwordx4 %7, %15, off sc0 sc1\n\t"
      "s_waitcnt vmcnt(0)"
      : "=&v"(v8),"=&v"(v9),"=&v"(v10),"=&v"(v11),
        "=&v"(v12),"=&v"(v13),"=&v"(v14),"=&v"(v15)
      : "v"(s[8]),"v"(s[9]),"v"(s[10]),"v"(s[11]),
        "v"(s[12]),"v"(s[13]),"v"(s[14]),"v"(s[15])
      : "memory");
    __builtin_amdgcn_sched_barrier(0);
    f32x4 vv[16] = {v0,v1,v2,v3,v4,v5,v6,v7,v8,v9,v10,v11,v12,v13,v14,v15};
#pragma unroll
    for (int i = 0; i < 16; ++i) {
      const int f = tid + (i << 8);
      *(f32x4*)&As[f >> 6][(f & 63) << 2] = vv[i];
    }
  } else {
#pragma unroll
    for (int i = 0; i < 16; ++i) {
      const int f = tid + (i << 8);
      *(f32x4*)&As[f >> 6][(f & 63) << 2] =
          *(const f32x4*)(Asrc + (size_t)(f >> 6) * NH + k0 + ((f & 63) << 2));
    }
  }
  // ---- stage W: 32x256 floats = 2048 f32x4, 8 per thread (cached) ----
#pragma unroll
  for (int i = 0; i < 8; ++i) {
    const int f = tid + (i << 8);
    *(f32x4*)&Ws[f >> 6][(f & 63) << 2] =
        *(const f32x4*)(W + (size_t)(n0 + (f >> 6)) * ldw + k0 + ((f & 63) << 2));
  }
  __syncthreads();
  // ---- compute ----
  const int tm = tid & 31, tn = tid >> 5;
  float acc[2][4] = {{0.f,0.f,0.f,0.f},{0.f,0.f,0.f,0.f}};
#pragma unroll 2
  for (int q = 0; q < 64; ++q) {
    f32x4 a0 = *(const f32x4*)&As[tm][q << 2];
    f32x4 a1 = *(const f32x4*)&As[tm + 32][q << 2];
#pragma unroll
    for (int jj = 0; jj < 4; ++jj) {
      f32x4 w4 = *(const f32x4*)&Ws[(tn << 2) + jj][q << 2];
      float t0 = acc[0][jj];
      t0 = fmaf(a0.x, w4.x, t0); t0 = fmaf(a0.y, w4.y, t0);
      t0 = fmaf(a0.z, w4.z, t0); t0 = fmaf(a0.w, w4.w, t0);
      acc[0][jj] = t0;
      float t1 = acc[1][jj];
      t1 = fmaf(a1.x, w4.x, t1); t1 = fmaf(a1.y, w4.y, t1);
      t1 = fmaf(a1.z, w4.z, t1); t1 = fmaf(a1.w, w4.w, t1);
      acc[1][jj] = t1;
    }
  }
  __syncthreads();
  f32x4 r0 = {acc[0][0], acc[0][1], acc[0][2], acc[0][3]};
  f32x4 r1 = {acc[1][0], acc[1][1], acc[1][2], acc[1][3]};
  float* p0 = Cdst + (size_t)tm * 1536 + n0 + (tn << 2);
  stg4(p0, r0);
  stg4(p0 + 32 * 1536, r1);
}

// ---------------------------------------------------------------------------
// Recurrence. 256 blocks x 256 threads, cooperative (co-residency only).
// Rows (blk<64, b=blk):  wait gh[t]+gi[t] -> gates (12-load batch, float4 x
//   128 threads) -> h -> hdone -> scores/softmax/ctx (cached, L2-warm) ->
//   u-matvec -> attn -> adone.
// gh-set (blk 64..159):  wait hdone[t] -> gh[t+1] = h @ W_hh^T   (overlaps
//   the rows' attention path). Prologue: gh[0] from enc_final (cached).
// gi-set (blk 160..255): wait adone[t] -> gi[t+1] = attn @ W_ihh^T.
// gi[0] == 0 exactly (attn^0 == 0) -> skipped.
// Flags layout (ints): [t*256 + {gh:0..95 | gi:96..191}] t=0..18 ;
//   hdone at 5120 + t*64 + b ; adone at 6400 + t*64 + b.
// ---------------------------------------------------------------------------
__global__ __launch_bounds__(256) void recur_kernel(
    const float* __restrict__ gi_emb, float* __restrict__ giA2,
    float* __restrict__ ghA2, float* __restrict__ hglob,
    float* __restrict__ attn_arr, const float* __restrict__ enc_proj,
    const float* __restrict__ enc_proj2, const float* __restrict__ enc_final,
    const int* __restrict__ len_src, const float* __restrict__ W_ih,
    const float* __restrict__ W_hh, const float* __restrict__ b_hh,
    const float* __restrict__ W_concat, const float* __restrict__ b_concat,
    int* __restrict__ flags)
{
  const int blk = blockIdx.x;
  const int tid = threadIdx.x;
  __shared__ float As[64][260];
  __shared__ float Ws[32][260];
  __shared__ float hstate[NH];
  __shared__ float uext[NH];
  __shared__ float scs[NS];
  __shared__ float aw[NS];

  if (blk >= 160) {
    // ---------------- gi-set ----------------
    const int hj = blk - 160;
    const int n0 = (hj >> 1) * 32, kh = hj & 1, k0 = kh * 256;
    float* giD = giA2 + kh * 98304;
    for (int t = 0; t + 1 < TSTEPS; ++t) {
      wait_n(flags + 6400 + t * 64, 64);
      gemm_helper<1>(attn_arr + (size_t)t * NB * NH, W_ih + NE, NE + NH,
                     giD, n0, k0, As, Ws);
      flag_publish(flags + (t + 1) * 256 + 96 + hj);
    }
    return;
  }
  if (blk >= 64) {
    // ---------------- gh-set ----------------
    const int hj = blk - 64;
    const int n0 = (hj >> 1) * 32, kh = hj & 1, k0 = kh * 256;
    float* ghD = ghA2 + kh * 98304;
    gemm_helper<0>(enc_final, W_hh, NH, ghD, n0, k0, As, Ws);
    flag_publish(flags + hj);
    for (int t = 0; t + 1 < TSTEPS; ++t) {
      wait_n(flags + 5120 + t * 64, 64);
      gemm_helper<1>(hglob, W_hh, NH, ghD, n0, k0, As, Ws);
      flag_publish(flags + (t + 1) * 256 + hj);
    }
    return;
  }

  // ---------------- rows ----------------
  const int b = blk;
  hstate[tid]       = enc_final[(size_t)b * NH + tid];
  hstate[tid + 256] = enc_final[(size_t)b * NH + tid + 256];
  __syncthreads();
  const int mylen = len_src[b];

  for (int t = 0; t < TSTEPS; ++t) {
    if (t == 0) wait_n(flags, 96);
    else        wait_n(flags + t * 256, 192);

    // ---- GRU gates: h^{t+1} (128 threads x float4) ----
    if (tid < 128) {
      const int j = tid << 2;
      const float* ge = gi_emb + (size_t)(t * NB + b) * 1536;
      f32x4 er = *(const f32x4*)(ge + j);
      f32x4 ez = *(const f32x4*)(ge + 512 + j);
      f32x4 en = *(const f32x4*)(ge + 1024 + j);
      f32x4 br = *(const f32x4*)(b_hh + j);
      f32x4 bz = *(const f32x4*)(b_hh + 512 + j);
      f32x4 bn = *(const f32x4*)(b_hh + 1024 + j);
      const size_t base = (size_t)b * 1536 + j;
      f32x4 I0,I1,I2,I3,I4,I5, G0,G1,G2,G3,G4,G5;
      if (t > 0) {
        const float* q0 = giA2 + base;          const float* q1 = q0 + 512;
        const float* q2 = q0 + 1024;
        const float* q3 = giA2 + 98304 + base;  const float* q4 = q3 + 512;
        const float* q5 = q3 + 1024;
        const float* r0 = ghA2 + base;          const float* r1 = r0 + 512;
        const float* r2 = r0 + 1024;
        const float* r3 = ghA2 + 98304 + base;  const float* r4 = r3 + 512;
        const float* r5 = r3 + 1024;
        asm volatile(
          "global_load_dwordx4 %0, %12, off sc0 sc1\n\t"
          "global_load_dwordx4 %1, %13, off sc0 sc1\n\t"
          "global_load_dwordx4 %2, %14, off sc0 sc1\n\t"
          "global_load_dwordx4 %3, %15, off sc0 sc1\n\t"
          "global_load_dwordx4 %4, %16, off sc0 sc1\n\t"
          "global_load_dwordx4 %5, %17, off sc0 sc1\n\t"
          "global_load_dwordx4 %6, %18, off sc0 sc1\n\t"
          "global_load_dwordx4 %7, %19, off sc0 sc1\n\t"
          "global_load_dwordx4 %8, %20, off sc0 sc1\n\t"
          "global_load_dwordx4 %9, %21, off sc0 sc1\n\t"
          "global_load_dwordx4 %10, %22, off sc0 sc1\n\t"
          "global_load_dwordx4 %11, %23, off sc0 sc1\n\t"
          "s_waitcnt vmcnt(0)"
          : "=&v"(I0),"=&v"(I1),"=&v"(I2),"=&v"(I3),"=&v"(I4),"=&v"(I5),
            "=&v"(G0),"=&v"(G1),"=&v"(G2),"=&v"(G3),"=&v"(G4),"=&v"(G5)
          : "v"(q0),"v"(q1),"v"(q2),"v"(q3),"v"(q4),"v"(q5),
            "v"(r0),"v"(r1),"v"(r2),"v"(r3),"v"(r4),"v"(r5)
          : "memory");
      } else {
        const float* r0 = ghA2 + base;          const float* r1 = r0 + 512;
        const float* r2 = r0 + 1024;
        const float* r3 = ghA2 + 98304 + base;  const float* r4 = r3 + 512;
        const float* r5 = r3 + 1024;
        asm volatile(
          "global_load_dwordx4 %0, %6, off sc0 sc1\n\t"
          "global_load_dwordx4 %1, %7, off sc0 sc1\n\t"
          "global_load_dwordx4 %2, %8, off sc0 sc1\n\t"
          "global_load_dwordx4 %3, %9, off sc0 sc1\n\t"
          "global_load_dwordx4 %4, %10, off sc0 sc1\n\t"
          "global_load_dwordx4 %5, %11, off sc0 sc1\n\t"
          "s_waitcnt vmcnt(0)"
          : "=&v"(G0),"=&v"(G1),"=&v"(G2),"=&v"(G3),"=&v"(G4),"=&v"(G5)
          : "v"(r0),"v"(r1),"v"(r2),"v"(r3),"v"(r4),"v"(r5)
          : "memory");
        I0 = I1 = I2 = I3 = I4 = I5 = (f32x4){0.f, 0.f, 0.f, 0.f};
      }
      __builtin_amdgcn_sched_barrier(0);
      f32x4 GR = I0 + I3 + er;
      f32x4 GZ = I1 + I4 + ez;
      f32x4 GN = I2 + I5 + en;
      f32x4 HR = G0 + G3 + br;
      f32x4 HZ = G1 + G4 + bz;
      f32x4 HN = G2 + G5 + bn;
      f32x4 hold = *(f32x4*)&hstate[j];
      f32x4 hv;
#define GATEC(c) { \
      float r_ = 1.f / (1.f + expf(-(GR.c + HR.c))); \
      float z_ = 1.f / (1.f + expf(-(GZ.c + HZ.c))); \
      float n_ = tanhf(GN.c + r_ * HN.c); \
      hv.c = (1.f - z_) * n_ + z_ * hold.c; }
      GATEC(x) GATEC(y) GATEC(z) GATEC(w)
#undef GATEC
      *(f32x4*)&hstate[j] = hv;
      stg4(hglob + (size_t)b * NH + j, hv);
    }
    flag_publish(flags + 5120 + t * 64 + b);    // h visible; hstate barriered

    // ---- attention scores (own row; cached enc_proj, L2-warm) ----
    {
      const int s = tid >> 2, sub = tid & 3;
      const float* ep = enc_proj + ((size_t)s * NB + b) * NH + sub * 4;
      float acc = 0.f;
#pragma unroll 8
      for (int i = 0; i < 32; ++i) {
        f32x4 e4 = *(const f32x4*)(ep + i * 16);
        f32x4 h4 = *(const f32x4*)&hstate[i * 16 + sub * 4];
        acc = fmaf(e4.x, h4.x, acc); acc = fmaf(e4.y, h4.y, acc);
        acc = fmaf(e4.z, h4.z, acc); acc = fmaf(e4.w, h4.w, acc);
      }
      acc += __shfl_xor(acc, 1);
      acc += __shfl_xor(acc, 2);
      if (sub == 0) scs[s] = acc;
    }
    __syncthreads();
    // ---- masked softmax (wave 0) ----
    if (tid < 64) {
      float v = (tid < mylen) ? scs[tid] : -1e9f;
      float mm = v;
      for (int off = 32; off >= 1; off >>= 1) mm = fmaxf(mm, __shfl_xor(mm, off));
      float e = expf(v - mm);
      float ssum = e;
      for (int off = 32; off >= 1; off >>= 1) ssum += __shfl_xor(ssum, off);
      aw[tid] = e / ssum;
    }
    __syncthreads();
    // ---- ctx-part: sum_s aw[s]*enc_proj2[s][b][:]  (== Wc_c @ ctx) ----
    float c0 = 0.f, c1 = 0.f;
#pragma unroll 4
    for (int s2 = 0; s2 < NS; ++s2) {
      const float w = aw[s2];
      const float* e2 = enc_proj2 + ((size_t)s2 * NB + b) * NH;
      c0 = fmaf(w, e2[tid], c0);
      c1 = fmaf(w, e2[tid + 256], c1);
    }
    // ---- u-matvec (own row, cached W_concat h-half) ----
#pragma unroll
    for (int h2 = 0; h2 < 2; ++h2) {
      const int n = tid + h2 * 256;
      const float* wr = W_concat + (size_t)n * (2 * NH);
      float acc = 0.f;
      for (int k = 0; k < NH; k += 4) {
        f32x4 w4 = *(const f32x4*)(wr + k);
        acc = fmaf(w4.x, hstate[k],     acc);
        acc = fmaf(w4.y, hstate[k + 1], acc);
        acc = fmaf(w4.z, hstate[k + 2], acc);
        acc = fmaf(w4.w, hstate[k + 3], acc);
      }
      uext[n] = acc + b_concat[n] + (h2 ? c1 : c0);
    }
    __syncthreads();
    // ---- attn^{t+1} = tanh(u), vectorized store ----
    if (tid < 128) {
      const int j = tid << 2;
      f32x4 u4 = *(f32x4*)&uext[j];
      f32x4 a4 = {tanhf(u4.x), tanhf(u4.y), tanhf(u4.z), tanhf(u4.w)};
      stg4(attn_arr + ((size_t)t * NB + b) * NH + j, a4);
    }
    flag_publish(flags + 6400 + t * 64 + b);
  }
}

// ---------------------------------------------------------------------------
// Online single-pass log-softmax + argmax per row (1216 rows).
// ---------------------------------------------------------------------------
__global__ __launch_bounds__(256) void row_softmax_kernel(
    float* __restrict__ out, float* __restrict__ words)
{
  const int row = blockIdx.x;
  const int tid = threadIdx.x;
  float* p = out + (size_t)row * NV;
  __shared__ float sm[256];
  __shared__ int   si[256];
  __shared__ float ss[256];

  float mv = -INFINITY; int mi = 0; float s = 0.f;
  for (int i = tid; i < NV; i += 256) {
    float v = p[i];
    if (v > mv) {
      s = s * expf(mv - v) + 1.f;
      mv = v; mi = i;
    } else {
      s += expf(v - mv);
    }
  }
  sm[tid] = mv; si[tid] = mi; ss[tid] = s;
  __syncthreads();
  for (int off = 128; off >= 1; off >>= 1) {
    if (tid < off) {
      float m1 = sm[tid], m2 = sm[tid + off];
      float s1 = ss[tid], s2 = ss[tid + off];
      int   i1 = si[tid], i2 = si[tid + off];
      float M = fmaxf(m1, m2);
      ss[tid] = s1 * expf(m1 - M) + s2 * expf(m2 - M);
      if (m2 > m1 || (m2 == m1 && i2 < i1)) { sm[tid] = m2; si[tid] = i2; }
    }
    __syncthreads();
  }
  const float lse = sm[0] + logf(ss[0]);
  for (int i = tid; i < NV; i += 256) p[i] -= lse;
  if (tid == 0) words[row] = (float)si[0];
}

// init: zero the write-once flag arrays (every launch, stream-ordered).
__global__ __launch_bounds__(256) void init_kernel(int* __restrict__ flags)
{
  int i = blockIdx.x * 256 + threadIdx.x;
  if (i < 8192)
    __hip_atomic_store(flags + i, 0, __ATOMIC_RELAXED, __HIP_MEMORY_SCOPE_SYSTEM);
}

extern "C" void kernel_launch(void* const* d_in, const int* in_sizes, int n_in,
                              void* d_out, int out_size, void* d_ws, size_t ws_size,
                              hipStream_t stream) {
  const int*   tgt       = (const int*)d_in[0];
  const int*   len_src   = (const int*)d_in[1];
  const float* enc_final = (const float*)d_in[3];
  const float* enc_out   = (const float*)d_in[4];
  const float* emb       = (const float*)d_in[6];
  const float* W_ih      = (const float*)d_in[7];
  const float* W_hh      = (const float*)d_in[8];
  const float* b_ih      = (const float*)d_in[9];
  const float* b_hh      = (const float*)d_in[10];
  const float* W_attn    = (const float*)d_in[11];
  const float* W_concat  = (const float*)d_in[12];
  const float* b_concat  = (const float*)d_in[13];
  const float* W_out     = (const float*)d_in[14];
  const float* b_out     = (const float*)d_in[15];
  float* out = (float*)d_out;

  // ---- workspace ----
  float* ws = (float*)d_ws;
  float* enc_proj = ws;                         // 64*64*512   = 2,097,152
  float* gi_emb   = ws + 2097152;               // 1216*1536   = 1,867,776
  float* attn_arr = ws + 3964928;               // 19*64*512   =   622,592

  // ---- scratch parked in the tail of d_out's logits region (free until
  //      logits_kernel runs; stream order guarantees no overlap in time) ----
  const size_t LOGF = (size_t)TSTEPS * NB * NV;        // 38,912,000 floats
  float* tail = out + (LOGF - 2560000);
  float* enc_proj2 = tail;                      // 2,097,152
  float* giA2  = enc_proj2 + 2097152;           //   196,608 (2 x 64x1536)
  float* ghA2  = giA2 + 196608;                 //   196,608
  float* hglob = ghA2 + 196608;                 //    32,768
  int*   flags = (int*)(hglob + 32768);         //     8,192 ints

  init_kernel<<<32, 256, 0, stream>>>(flags);

  // enc_proj  = enc_out @ W_attn^T                 (4096 x 512, K=512)
  linear_kernel<<<dim3(4, 64), 256, 0, stream>>>(
      enc_out, 512, W_attn, 512, nullptr, enc_proj, 512, 512, 0);

  // enc_proj2 = enc_out @ W_concat[:,512:]^T       (ctx-half of concat, linear)
  linear_kernel<<<dim3(4, 64), 256, 0, stream>>>(
      enc_out, 512, W_concat + 512, 1024, nullptr, enc_proj2, 512, 512, 0);

  // gi_emb = emb[tgt] @ W_ih[:, :256]^T + b_ih     (1216 x 1536, K=256)
  emb_linear_kernel<<<dim3(12, 19), 256, 0, stream>>>(
      emb, tgt, W_ih, b_ih, gi_emb);

  // whole recurrence: one cooperative kernel, flag-chained
  void* kargs[] = {
    (void*)&gi_emb, (void*)&giA2, (void*)&ghA2, (void*)&hglob,
    (void*)&attn_arr, (void*)&enc_proj, (void*)&enc_proj2, (void*)&enc_final,
    (void*)&len_src, (void*)&W_ih, (void*)&W_hh, (void*)&b_hh,
    (void*)&W_concat, (void*)&b_concat, (void*)&flags
  };
  hipLaunchCooperativeKernel((const void*)recur_kernel, dim3(256), dim3(256),
                             kargs, 0, stream);

  // logits for all steps: (1216 x 512) @ (512 x 32000), XCD-swizzled
  logits_kernel<<<4864, 256, 0, stream>>>(attn_arr, W_out, b_out, out);

  // online log-softmax + argmax words
  row_softmax_kernel<<<TSTEPS * NB, 256, 0, stream>>>(out, out + LOGF);
}

// Round 4
// 1964.379 us; speedup vs baseline: 1.9627x; 1.0194x over previous
//
#include <hip/hip_runtime.h>
#include <math.h>

// Problem constants
#define TSTEPS 19   // T-1 decode steps
#define NB 64       // batch
#define NS 64       // src len
#define NT 20       // tgt len
#define NH 512      // hidden
#define NE 256      // emb dim
#define NV 32000    // vocab

typedef float f32x4 __attribute__((ext_vector_type(4)));

// ---------------------------------------------------------------------------
// Cross-block dataflow: WRITES are sc0/sc1 bypass (write-through to MALL,
// no cache maintenance ever needed). READS are normal CACHED loads, safe
// because every cross-block buffer is t-VERSIONED (first-touch addresses
// each step -> no stale L2 line can exist; flag-gating orders RAW; the
// dispatch-boundary acquire invalidates L2 across launches). This removes
// the 48-way duplicated uncached-read hot-spotting that bounded round 3.
// Flags stay uncached (they are re-polled, so they must bypass).
// ---------------------------------------------------------------------------
__device__ __forceinline__ int ldi_sys(const int* p) {
  return __hip_atomic_load(p, __ATOMIC_RELAXED, __HIP_MEMORY_SCOPE_SYSTEM);
}
__device__ __forceinline__ void sti_sys(int* p, int v) {
  __hip_atomic_store(p, v, __ATOMIC_RELAXED, __HIP_MEMORY_SCOPE_SYSTEM);
}
__device__ __forceinline__ void vmfence() {
  asm volatile("s_waitcnt vmcnt(0)" ::: "memory");
}
__device__ __forceinline__ void stg4(float* p, f32x4 v) {
  asm volatile("global_store_dwordx4 %0, %1, off sc0 sc1" :: "v"(p), "v"(v) : "memory");
}
// all data stores drained (per-wave), block barrier, then tid0 sets flag=1
__device__ __forceinline__ void flag_publish(int* f) {
  vmfence();
  __syncthreads();
  if (threadIdx.x == 0) sti_sys(f, 1);
  asm volatile("" ::: "memory");
}
// wave0 polls n write-once flags, ballot-combined; others park at barrier.
__device__ __forceinline__ void wait_n(const int* f, int n) {
  if (threadIdx.x < 64) {
    for (;;) {
      int ok = 1;
      for (int i = threadIdx.x; i < n; i += 64) ok &= ldi_sys(f + i);
      if (__all(ok)) break;
      __builtin_amdgcn_s_sleep(1);
    }
  }
  __syncthreads();
  asm volatile("" ::: "memory");
}

// ---------------------------------------------------------------------------
// Generic fp32 linear: C[M,N] = A[M,K] @ W[N,K]^T (+bias). BM=64, BN=128.
// ---------------------------------------------------------------------------
__global__ __launch_bounds__(256) void linear_kernel(
    const float* __restrict__ A, int lda,
    const float* __restrict__ W, int ldw,
    const float* __restrict__ bias,
    float* __restrict__ C, int ldc,
    int K, int act)
{
  __shared__ float As[16][68];
  __shared__ float Ws[16][132];
  const int tid = threadIdx.x;
  const int m0 = blockIdx.y * 64;
  const int n0 = blockIdx.x * 128;
  const int lr = tid >> 2;
  const int lc = (tid & 3) << 2;
  const int tm = tid & 15;
  const int tn = tid >> 4;

  float acc[4][8];
#pragma unroll
  for (int i = 0; i < 4; ++i)
#pragma unroll
    for (int j = 0; j < 8; ++j) acc[i][j] = 0.f;

  const float* Ar  = A + (size_t)(m0 + lr) * lda + lc;
  const float* Wr0 = W + (size_t)(n0 + lr) * ldw + lc;
  const float* Wr1 = W + (size_t)(n0 + 64 + lr) * ldw + lc;

  for (int kk = 0; kk < K; kk += 16) {
    float4 av = *(const float4*)(Ar + kk);
    float4 w0 = *(const float4*)(Wr0 + kk);
    float4 w1 = *(const float4*)(Wr1 + kk);
    As[lc+0][lr] = av.x; As[lc+1][lr] = av.y; As[lc+2][lr] = av.z; As[lc+3][lr] = av.w;
    Ws[lc+0][lr] = w0.x; Ws[lc+1][lr] = w0.y; Ws[lc+2][lr] = w0.z; Ws[lc+3][lr] = w0.w;
    Ws[lc+0][64+lr] = w1.x; Ws[lc+1][64+lr] = w1.y; Ws[lc+2][64+lr] = w1.z; Ws[lc+3][64+lr] = w1.w;
    __syncthreads();
#pragma unroll
    for (int k = 0; k < 16; ++k) {
      float4 a4 = *(const float4*)&As[k][tm * 4];
      float4 b4 = *(const float4*)&Ws[k][tn * 8];
      float4 b5 = *(const float4*)&Ws[k][tn * 8 + 4];
      float a[4] = {a4.x, a4.y, a4.z, a4.w};
      float b[8] = {b4.x, b4.y, b4.z, b4.w, b5.x, b5.y, b5.z, b5.w};
#pragma unroll
      for (int i = 0; i < 4; ++i)
#pragma unroll
        for (int j = 0; j < 8; ++j)
          acc[i][j] = fmaf(a[i], b[j], acc[i][j]);
    }
    __syncthreads();
  }

#pragma unroll
  for (int i = 0; i < 4; ++i) {
    int m = m0 + tm * 4 + i;
    float* crow = C + (size_t)m * ldc + n0 + tn * 8;
    float vv[8];
#pragma unroll
    for (int j = 0; j < 8; ++j) {
      float v = acc[i][j];
      if (bias) v += bias[n0 + tn * 8 + j];
      if (act == 1) v = tanhf(v);
      vv[j] = v;
    }
    *(float4*)(crow)     = make_float4(vv[0], vv[1], vv[2], vv[3]);
    *(float4*)(crow + 4) = make_float4(vv[4], vv[5], vv[6], vv[7]);
  }
}

// ---------------------------------------------------------------------------
// gi_emb[t*64+b][:] = emb[tgt[b][t]] @ W_ih[:, :256]^T + b_ih   (1216 x 1536)
// ---------------------------------------------------------------------------
__global__ __launch_bounds__(256) void emb_linear_kernel(
    const float* __restrict__ emb, const int* __restrict__ tgt,
    const float* __restrict__ W_ih, const float* __restrict__ b_ih,
    float* __restrict__ C)
{
  __shared__ float As[16][68];
  __shared__ float Ws[16][132];
  const int tid = threadIdx.x;
  const int m0 = blockIdx.y * 64;
  const int n0 = blockIdx.x * 128;
  const int lr = tid >> 2;
  const int lc = (tid & 3) << 2;
  const int tm = tid & 15;
  const int tn = tid >> 4;

  float acc[4][8];
#pragma unroll
  for (int i = 0; i < 4; ++i)
#pragma unroll
    for (int j = 0; j < 8; ++j) acc[i][j] = 0.f;

  const int row = m0 + lr;                 // row = t*64 + b
  const int tok = tgt[(row & 63) * NT + (row >> 6)];
  const float* Ar  = emb + (size_t)tok * NE + lc;
  const float* Wr0 = W_ih + (size_t)(n0 + lr) * 768 + lc;
  const float* Wr1 = W_ih + (size_t)(n0 + 64 + lr) * 768 + lc;

  for (int kk = 0; kk < NE; kk += 16) {
    float4 av = *(const float4*)(Ar + kk);
    float4 w0 = *(const float4*)(Wr0 + kk);
    float4 w1 = *(const float4*)(Wr1 + kk);
    As[lc+0][lr] = av.x; As[lc+1][lr] = av.y; As[lc+2][lr] = av.z; As[lc+3][lr] = av.w;
    Ws[lc+0][lr] = w0.x; Ws[lc+1][lr] = w0.y; Ws[lc+2][lr] = w0.z; Ws[lc+3][lr] = w0.w;
    Ws[lc+0][64+lr] = w1.x; Ws[lc+1][64+lr] = w1.y; Ws[lc+2][64+lr] = w1.z; Ws[lc+3][64+lr] = w1.w;
    __syncthreads();
#pragma unroll
    for (int k = 0; k < 16; ++k) {
      float4 a4 = *(const float4*)&As[k][tm * 4];
      float4 b4 = *(const float4*)&Ws[k][tn * 8];
      float4 b5 = *(const float4*)&Ws[k][tn * 8 + 4];
      float a[4] = {a4.x, a4.y, a4.z, a4.w};
      float b[8] = {b4.x, b4.y, b4.z, b4.w, b5.x, b5.y, b5.z, b5.w};
#pragma unroll
      for (int i = 0; i < 4; ++i)
#pragma unroll
        for (int j = 0; j < 8; ++j)
          acc[i][j] = fmaf(a[i], b[j], acc[i][j]);
    }
    __syncthreads();
  }

#pragma unroll
  for (int i = 0; i < 4; ++i) {
    int m = m0 + tm * 4 + i;
    float* crow = C + (size_t)m * 1536 + n0 + tn * 8;
    float vv[8];
#pragma unroll
    for (int j = 0; j < 8; ++j) vv[j] = acc[i][j] + b_ih[n0 + tn * 8 + j];
    *(float4*)(crow)     = make_float4(vv[0], vv[1], vv[2], vv[3]);
    *(float4*)(crow + 4) = make_float4(vv[4], vv[5], vv[6], vv[7]);
  }
}

// ---------------------------------------------------------------------------
// Logits GEMM with XCD-ownership swizzle. C[1216,32000] = A @ W_out^T + b_out.
// ---------------------------------------------------------------------------
__global__ __launch_bounds__(256) void logits_kernel(
    const float* __restrict__ A, const float* __restrict__ W,
    const float* __restrict__ bias, float* __restrict__ C)
{
  const int bfl = blockIdx.x;
  const int xcd = bfl & 7;
  const int jj = bfl >> 3;
  const int mt = jj % 19;
  const int nt = xcd * 32 + jj / 19;
  if (nt >= 250) return;          // uniform whole-block exit before barriers
  const int m0 = mt * 64;
  const int n0 = nt * 128;

  __shared__ float As[16][68];
  __shared__ float Ws[16][132];
  const int tid = threadIdx.x;
  const int lr = tid >> 2;
  const int lc = (tid & 3) << 2;
  const int tm = tid & 15;
  const int tn = tid >> 4;

  float acc[4][8];
#pragma unroll
  for (int i = 0; i < 4; ++i)
#pragma unroll
    for (int j = 0; j < 8; ++j) acc[i][j] = 0.f;

  const float* Ar  = A + (size_t)(m0 + lr) * NH + lc;
  const float* Wr0 = W + (size_t)(n0 + lr) * NH + lc;
  const float* Wr1 = W + (size_t)(n0 + 64 + lr) * NH + lc;

  for (int kk = 0; kk < NH; kk += 16) {
    float4 av = *(const float4*)(Ar + kk);
    float4 w0 = *(const float4*)(Wr0 + kk);
    float4 w1 = *(const float4*)(Wr1 + kk);
    As[lc+0][lr] = av.x; As[lc+1][lr] = av.y; As[lc+2][lr] = av.z; As[lc+3][lr] = av.w;
    Ws[lc+0][lr] = w0.x; Ws[lc+1][lr] = w0.y; Ws[lc+2][lr] = w0.z; Ws[lc+3][lr] = w0.w;
    Ws[lc+0][64+lr] = w1.x; Ws[lc+1][64+lr] = w1.y; Ws[lc+2][64+lr] = w1.z; Ws[lc+3][64+lr] = w1.w;
    __syncthreads();
#pragma unroll
    for (int k = 0; k < 16; ++k) {
      float4 a4 = *(const float4*)&As[k][tm * 4];
      float4 b4 = *(const float4*)&Ws[k][tn * 8];
      float4 b5 = *(const float4*)&Ws[k][tn * 8 + 4];
      float a[4] = {a4.x, a4.y, a4.z, a4.w};
      float b[8] = {b4.x, b4.y, b4.z, b4.w, b5.x, b5.y, b5.z, b5.w};
#pragma unroll
      for (int i = 0; i < 4; ++i)
#pragma unroll
        for (int j = 0; j < 8; ++j)
          acc[i][j] = fmaf(a[i], b[j], acc[i][j]);
    }
    __syncthreads();
  }

#pragma unroll
  for (int i = 0; i < 4; ++i) {
    int m = m0 + tm * 4 + i;
    float* crow = C + (size_t)m * NV + n0 + tn * 8;
    float vv[8];
#pragma unroll
    for (int j = 0; j < 8; ++j) vv[j] = acc[i][j] + bias[n0 + tn * 8 + j];
    *(float4*)(crow)     = make_float4(vv[0], vv[1], vv[2], vv[3]);
    *(float4*)(crow + 4) = make_float4(vv[4], vv[5], vv[6], vv[7]);
  }
}

// ---------------------------------------------------------------------------
// Helper 64m x 32n x 256k GEMM (one split-K half), 512 threads.
// A (cross-block, t-versioned) and W (weights) both staged via CACHED f32x4
// loads: first block per XCD fetches lines into L2, the other ~11 share.
// Output: 1 bypassing dwordx4 per thread (4 cols x 1 row).
// ---------------------------------------------------------------------------
__device__ __forceinline__ void gemm_helper(
    const float* __restrict__ Asrc, const float* __restrict__ W, int ldw,
    float* __restrict__ Cdst, int n0, int k0,
    float (*As)[260], float (*Ws)[260])
{
  const int tid = threadIdx.x;
  // stage A: 64 x 256 floats = 4096 f32x4, 8 per thread
#pragma unroll
  for (int i = 0; i < 8; ++i) {
    const int f = tid + (i << 9);
    const int r = f >> 6, c = (f & 63) << 2;
    *(f32x4*)&As[r][c] = *(const f32x4*)(Asrc + (size_t)r * NH + k0 + c);
  }
  // stage W: 32 x 256 floats = 2048 f32x4, 4 per thread
#pragma unroll
  for (int i = 0; i < 4; ++i) {
    const int f = tid + (i << 9);
    const int r = f >> 6, c = (f & 63) << 2;
    *(f32x4*)&Ws[r][c] = *(const f32x4*)(W + (size_t)(n0 + r) * ldw + k0 + c);
  }
  __syncthreads();
  const int tm = tid & 63, tn = tid >> 6;   // 64 rows x 8 col-quads
  float acc[4] = {0.f, 0.f, 0.f, 0.f};
#pragma unroll 4
  for (int q = 0; q < 64; ++q) {
    f32x4 a4 = *(const f32x4*)&As[tm][q << 2];
#pragma unroll
    for (int j = 0; j < 4; ++j) {
      f32x4 w4 = *(const f32x4*)&Ws[(tn << 2) + j][q << 2];
      float t0 = acc[j];
      t0 = fmaf(a4.x, w4.x, t0); t0 = fmaf(a4.y, w4.y, t0);
      t0 = fmaf(a4.z, w4.z, t0); t0 = fmaf(a4.w, w4.w, t0);
      acc[j] = t0;
    }
  }
  __syncthreads();
  f32x4 r = {acc[0], acc[1], acc[2], acc[3]};
  stg4(Cdst + (size_t)tm * 1536 + n0 + (tn << 2), r);
}

// ---------------------------------------------------------------------------
// Recurrence. 256 blocks x 512 threads, cooperative (co-residency only).
// All cross-block buffers t-versioned; reads cached, writes bypass.
// Rows (blk<64, b=blk): wait gh[t](+gi[t]) -> gates -> h -> hbuf[t] ->
//   hdone -> scores/softmax/ctx/u (all own-row, L2-warm) -> attn_arr[t]
//   -> adone.
// gh-set (blk 64..159):  prologue gh[0]=enc_final@W_hh^T; then per t<18:
//   wait hdone[t] -> gh[t+1] = hbuf[t] @ W_hh^T (overlaps rows' attn path).
// gi-set (blk 160..255): per t<18: wait adone[t] -> gi[t+1] = attn[t]@W_ihh^T.
// gi[0] == 0 exactly (attn^0 == 0) -> skipped in gates at t=0.
// Flags: ghdone[t*192+hj], gidone[t*192+96+hj], hdone 3648+t*64+b,
//        adone 4864+t*64+b.
// ---------------------------------------------------------------------------
__global__ __launch_bounds__(512) void recur_kernel(
    const float* __restrict__ gi_emb, float* __restrict__ giP,
    float* __restrict__ ghP, float* __restrict__ hbuf,
    float* __restrict__ attn_arr, const float* __restrict__ enc_proj,
    const float* __restrict__ enc_proj2, const float* __restrict__ enc_final,
    const int* __restrict__ len_src, const float* __restrict__ W_ih,
    const float* __restrict__ W_hh, const float* __restrict__ b_hh,
    const float* __restrict__ W_concat, const float* __restrict__ b_concat,
    int* __restrict__ flags)
{
  const int blk = blockIdx.x;
  const int tid = threadIdx.x;
  __shared__ float As[64][260];
  __shared__ float Ws[32][260];
  __shared__ float hstate[NH];
  __shared__ float uext[NH];
  __shared__ float scs[NS];
  __shared__ float aw[NS];

  int* hdone = flags + 3648;
  int* adone = flags + 4864;

  if (blk >= 160) {
    // ---------------- gi-set ----------------
    const int hj = blk - 160;
    const int n0 = (hj >> 1) * 32, kh = hj & 1, k0 = kh * 256;
    for (int t = 0; t + 1 < TSTEPS; ++t) {
      wait_n(adone + t * 64, 64);
      gemm_helper(attn_arr + (size_t)t * NB * NH, W_ih + NE, NE + NH,
                  giP + (size_t)(t + 1) * 196608 + kh * 98304, n0, k0, As, Ws);
      flag_publish(flags + (t + 1) * 192 + 96 + hj);
    }
    return;
  }
  if (blk >= 64) {
    // ---------------- gh-set ----------------
    const int hj = blk - 64;
    const int n0 = (hj >> 1) * 32, kh = hj & 1, k0 = kh * 256;
    gemm_helper(enc_final, W_hh, NH, ghP + kh * 98304, n0, k0, As, Ws);
    flag_publish(flags + hj);
    for (int t = 0; t + 1 < TSTEPS; ++t) {
      wait_n(hdone + t * 64, 64);
      gemm_helper(hbuf + (size_t)t * NB * NH, W_hh, NH,
                  ghP + (size_t)(t + 1) * 196608 + kh * 98304, n0, k0, As, Ws);
      flag_publish(flags + (t + 1) * 192 + hj);
    }
    return;
  }

  // ---------------- rows ----------------
  const int b = blk;
  if (tid < 256) {
    hstate[tid]       = enc_final[(size_t)b * NH + tid];
    hstate[tid + 256] = enc_final[(size_t)b * NH + tid + 256];
  }
  __syncthreads();
  const int mylen = len_src[b];

  for (int t = 0; t < TSTEPS; ++t) {
    wait_n(flags + t * 192, t == 0 ? 96 : 192);

    // ---- GRU gates: h^{t+1} (128 threads x f32x4, cached partial reads) ----
    if (tid < 128) {
      const int j = tid << 2;
      const float* ge = gi_emb + (size_t)(t * NB + b) * 1536;
      f32x4 GR = *(const f32x4*)(ge + j);
      f32x4 GZ = *(const f32x4*)(ge + 512 + j);
      f32x4 GN = *(const f32x4*)(ge + 1024 + j);
      const size_t base = (size_t)b * 1536 + j;
      {
        const float* g0 = ghP + (size_t)t * 196608 + base;
        const float* g1 = g0 + 98304;
        f32x4 HR = *(const f32x4*)(b_hh + j)        + *(const f32x4*)(g0)
                 + *(const f32x4*)(g1);
        f32x4 HZ = *(const f32x4*)(b_hh + 512 + j)  + *(const f32x4*)(g0 + 512)
                 + *(const f32x4*)(g1 + 512);
        f32x4 HN = *(const f32x4*)(b_hh + 1024 + j) + *(const f32x4*)(g0 + 1024)
                 + *(const f32x4*)(g1 + 1024);
        if (t > 0) {
          const float* q0 = giP + (size_t)t * 196608 + base;
          const float* q1 = q0 + 98304;
          GR += *(const f32x4*)(q0)        + *(const f32x4*)(q1);
          GZ += *(const f32x4*)(q0 + 512)  + *(const f32x4*)(q1 + 512);
          GN += *(const f32x4*)(q0 + 1024) + *(const f32x4*)(q1 + 1024);
        }
        f32x4 hold = *(f32x4*)&hstate[j];
        f32x4 hv;
#define GATEC(c) { \
        float r_ = 1.f / (1.f + expf(-(GR.c + HR.c))); \
        float z_ = 1.f / (1.f + expf(-(GZ.c + HZ.c))); \
        float n_ = tanhf(GN.c + r_ * HN.c); \
        hv.c = (1.f - z_) * n_ + z_ * hold.c; }
        GATEC(x) GATEC(y) GATEC(z) GATEC(w)
#undef GATEC
        *(f32x4*)&hstate[j] = hv;
        stg4(hbuf + (size_t)t * NB * NH + (size_t)b * NH + j, hv);
      }
    }
    flag_publish(hdone + t * 64 + b);   // h in MALL; hstate barriered

    // ---- attention scores (own row; cached enc_proj, L2-warm) ----
    {
      const int s = tid >> 3, sub = tid & 7;
      const float* ep = enc_proj + ((size_t)s * NB + b) * NH + sub * 4;
      float acc = 0.f;
#pragma unroll
      for (int i = 0; i < 16; ++i) {
        f32x4 e4 = *(const f32x4*)(ep + i * 32);
        f32x4 h4 = *(const f32x4*)&hstate[i * 32 + sub * 4];
        acc = fmaf(e4.x, h4.x, acc); acc = fmaf(e4.y, h4.y, acc);
        acc = fmaf(e4.z, h4.z, acc); acc = fmaf(e4.w, h4.w, acc);
      }
      acc += __shfl_xor(acc, 1);
      acc += __shfl_xor(acc, 2);
      acc += __shfl_xor(acc, 4);
      if (sub == 0) scs[s] = acc;
    }
    __syncthreads();
    // ---- masked softmax (wave 0) ----
    if (tid < 64) {
      float v = (tid < mylen) ? scs[tid] : -1e9f;
      float mm = v;
      for (int off = 32; off >= 1; off >>= 1) mm = fmaxf(mm, __shfl_xor(mm, off));
      float e = expf(v - mm);
      float ssum = e;
      for (int off = 32; off >= 1; off >>= 1) ssum += __shfl_xor(ssum, off);
      aw[tid] = e / ssum;
    }
    __syncthreads();
    // ---- ctx-part (enc_proj2 trick) + u-matvec: one output n per thread ----
    {
      const int n = tid;
      float c = 0.f;
#pragma unroll 4
      for (int s2 = 0; s2 < NS; ++s2)
        c = fmaf(aw[s2], enc_proj2[(size_t)s2 * NB * NH + (size_t)b * NH + n], c);
      const float* wr = W_concat + (size_t)n * (2 * NH);
      float acc = 0.f;
      for (int k = 0; k < NH; k += 4) {
        f32x4 w4 = *(const f32x4*)(wr + k);
        acc = fmaf(w4.x, hstate[k],     acc);
        acc = fmaf(w4.y, hstate[k + 1], acc);
        acc = fmaf(w4.z, hstate[k + 2], acc);
        acc = fmaf(w4.w, hstate[k + 3], acc);
      }
      uext[n] = acc + b_concat[n] + c;
    }
    __syncthreads();
    // ---- attn^{t+1} = tanh(u), vectorized bypass store ----
    if (tid < 128) {
      const int j = tid << 2;
      f32x4 u4 = *(f32x4*)&uext[j];
      f32x4 a4 = {tanhf(u4.x), tanhf(u4.y), tanhf(u4.z), tanhf(u4.w)};
      stg4(attn_arr + ((size_t)t * NB + b) * NH + j, a4);
    }
    flag_publish(adone + t * 64 + b);
  }
}

// ---------------------------------------------------------------------------
// Online single-pass log-softmax + argmax per row (1216 rows).
// ---------------------------------------------------------------------------
__global__ __launch_bounds__(256) void row_softmax_kernel(
    float* __restrict__ out, float* __restrict__ words)
{
  const int row = blockIdx.x;
  const int tid = threadIdx.x;
  float* p = out + (size_t)row * NV;
  __shared__ float sm[256];
  __shared__ int   si[256];
  __shared__ float ss[256];

  float mv = -INFINITY; int mi = 0; float s = 0.f;
  for (int i = tid; i < NV; i += 256) {
    float v = p[i];
    if (v > mv) {
      s = s * expf(mv - v) + 1.f;
      mv = v; mi = i;
    } else {
      s += expf(v - mv);
    }
  }
  sm[tid] = mv; si[tid] = mi; ss[tid] = s;
  __syncthreads();
  for (int off = 128; off >= 1; off >>= 1) {
    if (tid < off) {
      float m1 = sm[tid], m2 = sm[tid + off];
      float s1 = ss[tid], s2 = ss[tid + off];
      int   i1 = si[tid], i2 = si[tid + off];
      float M = fmaxf(m1, m2);
      ss[tid] = s1 * expf(m1 - M) + s2 * expf(m2 - M);
      if (m2 > m1 || (m2 == m1 && i2 < i1)) { sm[tid] = m2; si[tid] = i2; }
    }
    __syncthreads();
  }
  const float lse = sm[0] + logf(ss[0]);
  for (int i = tid; i < NV; i += 256) p[i] -= lse;
  if (tid == 0) words[row] = (float)si[0];
}

// init: zero the write-once flag arrays (every launch, stream-ordered).
__global__ __launch_bounds__(256) void init_kernel(int* __restrict__ flags)
{
  int i = blockIdx.x * 256 + threadIdx.x;
  if (i < 8192)
    __hip_atomic_store(flags + i, 0, __ATOMIC_RELAXED, __HIP_MEMORY_SCOPE_SYSTEM);
}

extern "C" void kernel_launch(void* const* d_in, const int* in_sizes, int n_in,
                              void* d_out, int out_size, void* d_ws, size_t ws_size,
                              hipStream_t stream) {
  const int*   tgt       = (const int*)d_in[0];
  const int*   len_src   = (const int*)d_in[1];
  const float* enc_final = (const float*)d_in[3];
  const float* enc_out   = (const float*)d_in[4];
  const float* emb       = (const float*)d_in[6];
  const float* W_ih      = (const float*)d_in[7];
  const float* W_hh      = (const float*)d_in[8];
  const float* b_ih      = (const float*)d_in[9];
  const float* b_hh      = (const float*)d_in[10];
  const float* W_attn    = (const float*)d_in[11];
  const float* W_concat  = (const float*)d_in[12];
  const float* b_concat  = (const float*)d_in[13];
  const float* W_out     = (const float*)d_in[14];
  const float* b_out     = (const float*)d_in[15];
  float* out = (float*)d_out;

  // ---- workspace ----
  float* ws = (float*)d_ws;
  float* enc_proj = ws;                         // 64*64*512   = 2,097,152
  float* gi_emb   = ws + 2097152;               // 1216*1536   = 1,867,776
  float* attn_arr = ws + 3964928;               // 19*64*512   =   622,592

  // ---- t-versioned scratch parked in the tail of d_out's logits region
  //      (free until logits_kernel runs; stream order guarantees no overlap).
  const size_t LOGF = (size_t)TSTEPS * NB * NV;        // 38,912,000 floats
  const size_t SCRATCH = 2097152 + 3735552 + 3735552 + 622592 + 8192; // 10,199,040+8192
  float* tail = out + (LOGF - SCRATCH);
  float* enc_proj2 = tail;                      // 2,097,152
  float* ghP  = enc_proj2 + 2097152;            // 19 x 2 x 64 x 1536 = 3,735,552
  float* giP  = ghP + 3735552;                  // 3,735,552
  float* hbuf = giP + 3735552;                  // 19 x 64 x 512 = 622,592
  int*   flags = (int*)(hbuf + 622592);         // 8,192 ints

  init_kernel<<<32, 256, 0, stream>>>(flags);

  // enc_proj  = enc_out @ W_attn^T                 (4096 x 512, K=512)
  linear_kernel<<<dim3(4, 64), 256, 0, stream>>>(
      enc_out, 512, W_attn, 512, nullptr, enc_proj, 512, 512, 0);

  // enc_proj2 = enc_out @ W_concat[:,512:]^T       (ctx-half of concat, linear)
  linear_kernel<<<dim3(4, 64), 256, 0, stream>>>(
      enc_out, 512, W_concat + 512, 1024, nullptr, enc_proj2, 512, 512, 0);

  // gi_emb = emb[tgt] @ W_ih[:, :256]^T + b_ih     (1216 x 1536, K=256)
  emb_linear_kernel<<<dim3(12, 19), 256, 0, stream>>>(
      emb, tgt, W_ih, b_ih, gi_emb);

  // whole recurrence: one cooperative kernel, flag-chained, cached reads
  void* kargs[] = {
    (void*)&gi_emb, (void*)&giP, (void*)&ghP, (void*)&hbuf,
    (void*)&attn_arr, (void*)&enc_proj, (void*)&enc_proj2, (void*)&enc_final,
    (void*)&len_src, (void*)&W_ih, (void*)&W_hh, (void*)&b_hh,
    (void*)&W_concat, (void*)&b_concat, (void*)&flags
  };
  hipLaunchCooperativeKernel((const void*)recur_kernel, dim3(256), dim3(512),
                             kargs, 0, stream);

  // logits for all steps: (1216 x 512) @ (512 x 32000), XCD-swizzled
  logits_kernel<<<4864, 256, 0, stream>>>(attn_arr, W_out, b_out, out);

  // online log-softmax + argmax words
  row_softmax_kernel<<<TSTEPS * NB, 256, 0, stream>>>(out, out + LOGF);
}